// Round 5
// baseline (721.062 us; speedup 1.0000x reference)
//
#include <hip/hip_runtime.h>
#include <hip/hip_bf16.h>

typedef __attribute__((ext_vector_type(8))) short short8;
typedef __attribute__((ext_vector_type(4))) float f32x4;

__device__ __forceinline__ short f2bf(float f) {
  unsigned u = __float_as_uint(f);
  u += 0x7fffu + ((u >> 16) & 1u);   // RNE
  return (short)(u >> 16);
}

__device__ __forceinline__ void gload16(const short* g, short* l) {
  __builtin_amdgcn_global_load_lds(
      (const __attribute__((address_space(1))) unsigned int*)g,
      (__attribute__((address_space(3))) unsigned int*)l, 16, 0, 0);
}

// ---------------- L2 norm scale ------------------------------------------------------
__global__ __launch_bounds__(256) void l2norm_kernel(const float* __restrict__ f0,
                                                     float* __restrict__ scale,
                                                     int C, int P, int total) {
  __shared__ float red[4][64];
  int pl = threadIdx.x & 63;
  int cg = threadIdx.x >> 6;
  int pos = blockIdx.x * 64 + pl;
  float s = 0.f;
  if (pos < total) {
    int n = pos / P, sp = pos - n * P;
    const float* base = f0 + (size_t)n * C * P + sp;
    int c0 = cg * (C >> 2), c1 = c0 + (C >> 2);
    for (int c = c0; c < c1; ++c) {
      float v = base[(size_t)c * P];
      s += v * v;
    }
  }
  red[cg][pl] = s;
  __syncthreads();
  if (threadIdx.x < 64 && pos < total) {
    float tot = red[0][pl] + red[1][pl] + red[2][pl] + red[3][pl];
    scale[pos] = 1.0f / (sqrtf(tot) + 1e-10f);
  }
}

// ------------- NCHW fp32 -> padded NHWC bf16 -----------------------------------------
__global__ __launch_bounds__(256) void to_nhwc_kernel(const float* __restrict__ src,
    short* __restrict__ dst, const float* __restrict__ rowscale,
    const float* __restrict__ chw, int C, int H, int W, int Wp, int nstride, int hh) {
  __shared__ float tile[32][33];
  int n = blockIdx.z;
  int P = H * W;
  int p0 = blockIdx.x * 32, c0 = blockIdx.y * 32;
  int tp = threadIdx.x & 31, tr = threadIdx.x >> 5;
  const float* s = src + (size_t)n * C * P;
  #pragma unroll
  for (int i = 0; i < 4; ++i) {
    int cl = tr + i * 8;
    int p = p0 + tp;
    tile[cl][tp] = (p < P) ? s[(size_t)(c0 + cl) * P + p] : 0.f;
  }
  __syncthreads();
  #pragma unroll
  for (int i = 0; i < 4; ++i) {
    int pl = tr + i * 8;
    int p = p0 + pl;
    if (p >= P) continue;
    int c = c0 + tp;
    float v = tile[tp][pl];
    if (chw)      v *= chw[c];
    if (rowscale) v *= rowscale[n * P + p];
    int y = p / W, x = p - y * W;
    dst[((size_t)n * nstride + (y + hh) * Wp + (x + hh)) * C + c] = f2bf(v);
  }
}

// ---------------- weight repack ------------------------------------------------------
struct WSeg { const float* src; short* dst; int Ci; int S; int elems; };
struct WPrep { WSeg seg[20]; };

__global__ __launch_bounds__(256) void wprep_kernel(WPrep p, int total) {
  int i = blockIdx.x * 256 + threadIdx.x;
  if (i >= total) return;
  int local = i;
  int si = 0;
  while (local >= p.seg[si].elems) { local -= p.seg[si].elems; ++si; }
  WSeg sg = p.seg[si];
  int ci = local % sg.Ci;
  int q  = local / sg.Ci;
  int s  = q % sg.S;
  int co = q / sg.S;
  float v = sg.src[((size_t)co * sg.Ci + ci) * sg.S + s];
  sg.dst[local] = f2bf(v);
}

// ---------------- conv params --------------------------------------------------------
struct ConvP {
  const short* in;   // bf16 padded NHWC [16][iHp][iWp][Ci]
  const short* w;    // bf16 [Co][S][Ci]
  const float* b1;   // bias (extra) / cls bias (head)
  const float* b2;   // box bias (head)
  short* out_bf;     // extra: padded bf16 NHWC out
  float* out_f;      // head: packed d_out
  int M, Ci, iHp, iWp, Ho, Wo, Co;
  int S, kdim, stride, ioff;
  int oWp, onstride, oh;
  int mbox, row_base;
};

// ------- 3-buffer depth-2 counted-vmcnt implicit-GEMM core (48KB LDS at 128²) --------
// Schedule per iter: wait vmcnt(LPS) [own stage(ks) drained] -> s_barrier ->
// stage(ks+2) into buf (ks+2)%3 [WAR-safe: all waves consumed buf (ks-1)%3 pre-barrier]
// -> ds_read buf ks%3 -> setprio(1) MFMA setprio(0). One barrier/iter, never vmcnt(0)
// in steady state (T3+T4); T2 k-chunk XOR swizzle pre-applied on the GLOBAL address.
template<int BM, int BN, bool HEAD>
__device__ __forceinline__ void conv_core(const ConvP p, int bx, int by) {
  constexpr int NA = BM / 64, NB = BN / 64, AM = BM / 32, AN = BN / 32;
  constexpr int LPS = NA + NB;               // gload_lds per thread per stage
  constexpr int ABUF = BM * 32, BBUF = BN * 32;
  __shared__ short As[3 * ABUF];
  __shared__ short Bs[3 * BBUF];
  const int t = threadIdx.x, lane = t & 63, wave = t >> 6;
  const int HW = p.Ho * p.Wo;
  const int sr = t >> 2;
  const int slot = ((t & 3) ^ ((t >> 3) & 3)) * 8;   // T2: pre-swizzled global k-slot

  const short* aBase[NA];
  const short* bBase[NB];
  #pragma unroll
  for (int i = 0; i < NA; ++i) {
    int pos = bx * BM + sr + i * 64; if (pos >= p.M) pos = p.M - 1;
    int n = pos / HW, rem = pos - n * HW;
    int yo = rem / p.Wo, xo = rem - yo * p.Wo;
    aBase[i] = p.in + ((size_t)(n * p.iHp + yo * p.stride + p.ioff) * p.iWp
                      + xo * p.stride + p.ioff) * p.Ci + slot;
  }
  #pragma unroll
  for (int i = 0; i < NB; ++i) {
    int co = by * BN + sr + i * 64; if (co >= p.Co) co = p.Co - 1;
    bBase[i] = p.w + (size_t)co * p.S * p.Ci + slot;
  }
  const int cs = p.Ci >> 5;                  // 32-ci chunks per tap (power of 2)
  const int csh = 31 - __clz(cs);
  const int total = p.S * cs;

  auto stage = [&](int ks, int buf) {
    int aoff;
    if (p.S == 1) {
      aoff = ks * 32;
    } else {
      int tap = ks >> csh;
      int dy = tap / 3, dx = tap - dy * 3;
      aoff = (dy * p.iWp + dx) * p.Ci + (ks & (cs - 1)) * 32;
    }
    int boff = ks * 32;
    #pragma unroll
    for (int i = 0; i < NA; ++i)
      gload16(aBase[i] + aoff, &As[buf * ABUF + i * 2048 + t * 8]);
    #pragma unroll
    for (int i = 0; i < NB; ++i)
      gload16(bBase[i] + boff, &Bs[buf * BBUF + i * 2048 + t * 8]);
  };

  f32x4 acc[AM][AN];
  #pragma unroll
  for (int i = 0; i < AM; ++i)
    #pragma unroll
    for (int j = 0; j < AN; ++j)
      acc[i][j] = (f32x4){0.f, 0.f, 0.f, 0.f};

  const int wr = (wave >> 1) * (BM / 2), wc = (wave & 1) * (BN / 2);
  const int lrow = lane & 15, lchunk = lane >> 4;

  stage(0, 0);
  if (total > 1) stage(1, 1);

  int bufc = 0, bufs = 2;
  for (int ks = 0; ks < total; ++ks) {
    if (ks + 1 < total) {
      if constexpr (LPS == 4) asm volatile("s_waitcnt vmcnt(4)" ::: "memory");
      else                    asm volatile("s_waitcnt vmcnt(2)" ::: "memory");
    } else {
      asm volatile("s_waitcnt vmcnt(0)" ::: "memory");
    }
    __builtin_amdgcn_s_barrier();
    asm volatile("" ::: "memory");
    if (ks + 2 < total) stage(ks + 2, bufs);
    const short* aRd0 = &As[bufc * ABUF];
    const short* bRd0 = &Bs[bufc * BBUF];
    short8 a[AM], b[AN];
    #pragma unroll
    for (int i = 0; i < AM; ++i) {
      int r = wr + i * 16 + lrow;
      int ch = lchunk ^ ((r >> 1) & 3);      // T2 inverse swizzle on read
      a[i] = *reinterpret_cast<const short8*>(aRd0 + r * 32 + ch * 8);
    }
    #pragma unroll
    for (int j = 0; j < AN; ++j) {
      int r = wc + j * 16 + lrow;
      int ch = lchunk ^ ((r >> 1) & 3);
      b[j] = *reinterpret_cast<const short8*>(bRd0 + r * 32 + ch * 8);
    }
    __builtin_amdgcn_s_setprio(1);           // T5
    #pragma unroll
    for (int i = 0; i < AM; ++i)
      #pragma unroll
      for (int j = 0; j < AN; ++j)
        acc[i][j] = __builtin_amdgcn_mfma_f32_16x16x32_bf16(a[i], b[j], acc[i][j], 0, 0, 0);
    __builtin_amdgcn_s_setprio(0);
    bufc = (bufc == 2) ? 0 : bufc + 1;
    bufs = (bufs == 2) ? 0 : bufs + 1;
  }

  const int mk = p.mbox * 81;
  const int rb_ = (lane >> 4) * 4, cl_ = lane & 15;
  #pragma unroll
  for (int i = 0; i < AM; ++i)
    #pragma unroll
    for (int j = 0; j < AN; ++j)
      #pragma unroll
      for (int q = 0; q < 4; ++q) {
        int po = bx * BM + wr + i * 16 + rb_ + q;
        int co = by * BN + wc + j * 16 + cl_;
        if (po >= p.M || co >= p.Co) continue;
        float v = acc[i][j][q];
        if (!HEAD) {
          int n2 = po / HW, sp = po - n2 * HW;
          int y = sp / p.Wo, x = sp - y * p.Wo;
          float v2 = fmaxf(v + p.b1[co], 0.f);
          p.out_bf[((size_t)n2 * p.onstride + (y + p.oh) * p.oWp + (x + p.oh)) * p.Co + co] = f2bf(v2);
        } else {
          int n2 = po / HW, sp = po - n2 * HW;
          int mi, col; float bias;
          if (co < mk) { mi = co / 81; col = co - mi * 81; bias = p.b1[co]; }
          else { int cbx = co - mk; mi = cbx >> 2; col = 81 + (cbx & 3); bias = p.b2[cbx]; }
          size_t orow = (size_t)n2 * 8732 + p.row_base + (size_t)sp * p.mbox + mi;
          p.out_f[orow * 85 + col] = v + bias;
        }
      }
}

__global__ __launch_bounds__(256) void conv_tile64(ConvP p) {
  conv_core<64, 64, false>(p, blockIdx.x, blockIdx.y);
}

// ---------------- grouped head kernel (all 6 heads, one launch) ----------------------
struct HeadPack { ConvP L[6]; int blk0[6]; int nby[6]; };

__global__ __launch_bounds__(256) void head_grouped(HeadPack h, int nblk) {
  // T1: bijective chunked XCD swizzle (m204); logical order by-fast so an
  // A-panel's N-passes land on the same XCD's L2.
  int orig = blockIdx.x;
  int q = nblk >> 3, r = nblk & 7;
  int xcd = orig & 7, idx = orig >> 3;
  int wgid = (xcd < r ? xcd * (q + 1) : r * (q + 1) + (xcd - r) * q) + idx;
  int li = 0;
  #pragma unroll
  for (int i = 1; i < 6; ++i) if (wgid >= h.blk0[i]) li = i;
  int local = wgid - h.blk0[li];
  int by = local % h.nby[li];
  int bx = local / h.nby[li];
  conv_core<128, 128, true>(h.L[li], bx, by);
}

extern "C" void kernel_launch(void* const* d_in, const int* in_sizes, int n_in,
                              void* d_out, int out_size, void* d_ws, size_t ws_size,
                              hipStream_t stream) {
  const float* feat0 = (const float*)d_in[0];
  const float* feat1 = (const float*)d_in[1];
  const float* l2w   = (const float*)d_in[2];
  const float* ew[8]; const float* eb[8];
  for (int i = 0; i < 8; ++i) { ew[i] = (const float*)d_in[3 + 2 * i]; eb[i] = (const float*)d_in[4 + 2 * i]; }
  const float* cw[6]; const float* cb[6]; const float* bw[6]; const float* bb[6];
  for (int i = 0; i < 6; ++i) {
    cw[i] = (const float*)d_in[19 + 4 * i]; cb[i] = (const float*)d_in[20 + 4 * i];
    bw[i] = (const float*)d_in[21 + 4 * i]; bb[i] = (const float*)d_in[22 + 4 * i];
  }
  float* out = (float*)d_out;
  char* ws = (char*)d_ws;
  size_t off = 0;
  auto alloc = [&](size_t bytes) -> char* {
    char* p = ws + off;
    off = (off + bytes + 255) & ~(size_t)255;
    return p;
  };
  float* scale0 = (float*)alloc(23104 * 4);
  char* featStart = ws + off;
  short* f0b = (short*)alloc((size_t)16 * 40 * 40 * 512 * 2);   // 38x38, h=1
  short* f1b = (short*)alloc((size_t)16 * 21 * 21 * 1024 * 2);  // 19x19, h=1
  short* xe0 = (short*)alloc((size_t)16 * 21 * 21 * 256 * 2);   // 19x19, h=1
  short* f2b = (short*)alloc((size_t)16 * 12 * 12 * 512 * 2);   // 10x10, h=1
  short* xe2 = (short*)alloc((size_t)16 * 12 * 12 * 128 * 2);   // 10x10, h=1
  short* f3b = (short*)alloc((size_t)16 * 7 * 7 * 256 * 2);     // 5x5,  h=1
  short* xe4 = (short*)alloc((size_t)16 * 5 * 5 * 128 * 2);     // 5x5,  h=0
  short* f4b = (short*)alloc((size_t)16 * 5 * 5 * 256 * 2);     // 3x3,  h=1
  short* xe6 = (short*)alloc((size_t)16 * 3 * 3 * 128 * 2);     // 3x3,  h=0
  short* f5b = (short*)alloc((size_t)16 * 3 * 3 * 256 * 2);     // 1x1,  h=1
  size_t featBytes = (size_t)((ws + off) - featStart);

  static const int eCo[8] = {256, 512, 128, 256, 128, 256, 128, 256};
  static const int eCi[8] = {1024, 256, 512, 128, 256, 128, 256, 128};
  static const int eS[8]  = {1, 9, 1, 9, 1, 9, 1, 9};
  static const int mbox[6] = {4, 6, 6, 6, 4, 4};
  static const int hCi[6] = {512, 1024, 512, 256, 256, 256};

  WPrep wp; int total = 0; int segi = 0;
  short* ewb[8]; short* hwb[6];
  for (int i = 0; i < 8; ++i) {
    int e = eCo[i] * eCi[i] * eS[i];
    ewb[i] = (short*)alloc((size_t)e * 2);
    wp.seg[segi++] = {ew[i], ewb[i], eCi[i], eS[i], e};
    total += e;
  }
  for (int L = 0; L < 6; ++L) {
    int co = mbox[L] * 85;
    int e = co * hCi[L] * 9;
    hwb[L] = (short*)alloc((size_t)e * 2);
    int ecls = mbox[L] * 81 * hCi[L] * 9;
    wp.seg[segi++] = {cw[L], hwb[L], hCi[L], 9, ecls};
    wp.seg[segi++] = {bw[L], hwb[L] + (size_t)mbox[L] * 81 * 9 * hCi[L], hCi[L], 9, e - ecls};
    total += e;
  }

  hipMemsetAsync(featStart, 0, featBytes, stream);
  l2norm_kernel<<<dim3((23104 + 63) / 64), 256, 0, stream>>>(feat0, scale0, 512, 1444, 23104);
  to_nhwc_kernel<<<dim3(46, 16, 16), 256, 0, stream>>>(feat0, f0b, scale0, l2w, 512, 38, 38, 40, 1600, 1);
  to_nhwc_kernel<<<dim3(12, 32, 16), 256, 0, stream>>>(feat1, f1b, nullptr, nullptr, 1024, 19, 19, 21, 441, 1);
  wprep_kernel<<<dim3((total + 255) / 256), 256, 0, stream>>>(wp, total);

  auto mkP = [&](const short* in, const short* wbuf, const float* b1, const float* b2,
                 short* outb, float* outf, int Ci, int iHp, int iWp, int Ho, int Wo,
                 int Co, int S, int kd, int st, int ioff, int oWp, int onstride, int oh,
                 int m, int rb) {
    ConvP p{}; p.in = in; p.w = wbuf; p.b1 = b1; p.b2 = b2; p.out_bf = outb; p.out_f = outf;
    p.M = 16 * Ho * Wo; p.Ci = Ci; p.iHp = iHp; p.iWp = iWp; p.Ho = Ho; p.Wo = Wo; p.Co = Co;
    p.S = S; p.kdim = kd; p.stride = st; p.ioff = ioff;
    p.oWp = oWp; p.onstride = onstride; p.oh = oh; p.mbox = m; p.row_base = rb;
    return p;
  };
  auto run64 = [&](ConvP p) {
    conv_tile64<<<dim3((p.M + 63) / 64, (p.Co + 63) / 64), 256, 0, stream>>>(p);
  };

  // extras chain (depth-2 pipelined 64x64, 24KB LDS)
  run64(mkP(f1b, ewb[0], eb[0], nullptr, xe0, nullptr, 1024, 21, 21, 19, 19, 256, 1, 1, 1, 1, 21, 441, 1, 0, 0));
  run64(mkP(xe0, ewb[1], eb[1], nullptr, f2b, nullptr,  256, 21, 21, 10, 10, 512, 9, 3, 2, 0, 12, 144, 1, 0, 0));
  run64(mkP(f2b, ewb[2], eb[2], nullptr, xe2, nullptr,  512, 12, 12, 10, 10, 128, 1, 1, 1, 1, 12, 144, 1, 0, 0));
  run64(mkP(xe2, ewb[3], eb[3], nullptr, f3b, nullptr,  128, 12, 12,  5,  5, 256, 9, 3, 2, 0,  7,  49, 1, 0, 0));
  run64(mkP(f3b, ewb[4], eb[4], nullptr, xe4, nullptr,  256,  7,  7,  5,  5, 128, 1, 1, 1, 1,  5,  25, 0, 0, 0));
  run64(mkP(xe4, ewb[5], eb[5], nullptr, f4b, nullptr,  128,  5,  5,  3,  3, 256, 9, 3, 1, 0,  5,  25, 1, 0, 0));
  run64(mkP(f4b, ewb[6], eb[6], nullptr, xe6, nullptr,  256,  5,  5,  3,  3, 128, 1, 1, 1, 1,  3,   9, 0, 0, 0));
  run64(mkP(xe6, ewb[7], eb[7], nullptr, f5b, nullptr,  128,  3,  3,  1,  1, 256, 9, 3, 1, 0,  3,   9, 1, 0, 0));

  // all 6 heads in ONE launch; longest-K layer (head1) first for tail balance
  HeadPack h;
  h.L[0] = mkP(f1b, hwb[1], cb[1], bb[1], nullptr, out, 1024, 21, 21, 19, 19, 6 * 85, 9, 3, 1, 0, 0, 0, 0, 6, 5776);
  h.L[1] = mkP(f0b, hwb[0], cb[0], bb[0], nullptr, out,  512, 40, 40, 38, 38, 4 * 85, 9, 3, 1, 0, 0, 0, 0, 4, 0);
  h.L[2] = mkP(f2b, hwb[2], cb[2], bb[2], nullptr, out,  512, 12, 12, 10, 10, 6 * 85, 9, 3, 1, 0, 0, 0, 0, 6, 7942);
  h.L[3] = mkP(f3b, hwb[3], cb[3], bb[3], nullptr, out,  256,  7,  7,  5,  5, 6 * 85, 9, 3, 1, 0, 0, 0, 0, 6, 8542);
  h.L[4] = mkP(f4b, hwb[4], cb[4], bb[4], nullptr, out,  256,  5,  5,  3,  3, 4 * 85, 9, 3, 1, 0, 0, 0, 0, 4, 8692);
  h.L[5] = mkP(f5b, hwb[5], cb[5], bb[5], nullptr, out,  256,  3,  3,  1,  1, 4 * 85, 9, 3, 1, 0, 0, 0, 0, 4, 8728);
  int nblk = 0;
  for (int i = 0; i < 6; ++i) {
    h.blk0[i] = nblk;
    int nbx = (h.L[i].M + 127) / 128;
    h.nby[i] = (h.L[i].Co + 127) / 128;
    nblk += nbx * h.nby[i];
  }
  head_grouped<<<dim3(nblk), 256, 0, stream>>>(h, nblk);
}

// Round 6
// 700.941 us; speedup vs baseline: 1.0287x; 1.0287x over previous
//
#include <hip/hip_runtime.h>
#include <hip/hip_bf16.h>

typedef __attribute__((ext_vector_type(8))) short short8;
typedef __attribute__((ext_vector_type(4))) float f32x4;

__device__ __forceinline__ short f2bf(float f) {
  unsigned u = __float_as_uint(f);
  u += 0x7fffu + ((u >> 16) & 1u);   // RNE
  return (short)(u >> 16);
}

__device__ __forceinline__ void gload16(const short* g, short* l) {
  __builtin_amdgcn_global_load_lds(
      (const __attribute__((address_space(1))) unsigned int*)g,
      (__attribute__((address_space(3))) unsigned int*)l, 16, 0, 0);
}

// ---------------- L2 norm scale ------------------------------------------------------
__global__ __launch_bounds__(256) void l2norm_kernel(const float* __restrict__ f0,
                                                     float* __restrict__ scale,
                                                     int C, int P, int total) {
  __shared__ float red[4][64];
  int pl = threadIdx.x & 63;
  int cg = threadIdx.x >> 6;
  int pos = blockIdx.x * 64 + pl;
  float s = 0.f;
  if (pos < total) {
    int n = pos / P, sp = pos - n * P;
    const float* base = f0 + (size_t)n * C * P + sp;
    int c0 = cg * (C >> 2), c1 = c0 + (C >> 2);
    for (int c = c0; c < c1; ++c) {
      float v = base[(size_t)c * P];
      s += v * v;
    }
  }
  red[cg][pl] = s;
  __syncthreads();
  if (threadIdx.x < 64 && pos < total) {
    float tot = red[0][pl] + red[1][pl] + red[2][pl] + red[3][pl];
    scale[pos] = 1.0f / (sqrtf(tot) + 1e-10f);
  }
}

// ------------- NCHW fp32 -> padded NHWC bf16 -----------------------------------------
__global__ __launch_bounds__(256) void to_nhwc_kernel(const float* __restrict__ src,
    short* __restrict__ dst, const float* __restrict__ rowscale,
    const float* __restrict__ chw, int C, int H, int W, int Wp, int nstride, int hh) {
  __shared__ float tile[32][33];
  int n = blockIdx.z;
  int P = H * W;
  int p0 = blockIdx.x * 32, c0 = blockIdx.y * 32;
  int tp = threadIdx.x & 31, tr = threadIdx.x >> 5;
  const float* s = src + (size_t)n * C * P;
  #pragma unroll
  for (int i = 0; i < 4; ++i) {
    int cl = tr + i * 8;
    int p = p0 + tp;
    tile[cl][tp] = (p < P) ? s[(size_t)(c0 + cl) * P + p] : 0.f;
  }
  __syncthreads();
  #pragma unroll
  for (int i = 0; i < 4; ++i) {
    int pl = tr + i * 8;
    int p = p0 + pl;
    if (p >= P) continue;
    int c = c0 + tp;
    float v = tile[tp][pl];
    if (chw)      v *= chw[c];
    if (rowscale) v *= rowscale[n * P + p];
    int y = p / W, x = p - y * W;
    dst[((size_t)n * nstride + (y + hh) * Wp + (x + hh)) * C + c] = f2bf(v);
  }
}

// ---------------- weight repack ------------------------------------------------------
struct WSeg { const float* src; short* dst; int Ci; int S; int elems; };
struct WPrep { WSeg seg[20]; };

__global__ __launch_bounds__(256) void wprep_kernel(WPrep p, int total) {
  int i = blockIdx.x * 256 + threadIdx.x;
  if (i >= total) return;
  int local = i;
  int si = 0;
  while (local >= p.seg[si].elems) { local -= p.seg[si].elems; ++si; }
  WSeg sg = p.seg[si];
  int ci = local % sg.Ci;
  int q  = local / sg.Ci;
  int s  = q % sg.S;
  int co = q / sg.S;
  float v = sg.src[((size_t)co * sg.Ci + ci) * sg.S + s];
  sg.dst[local] = f2bf(v);
}

// ---------------- conv params --------------------------------------------------------
struct ConvP {
  const short* in;   // bf16 padded NHWC [16][iHp][iWp][Ci]
  const short* w;    // bf16 [Co][S][Ci]
  const float* b1;   // bias (extra) / cls bias (head)
  const float* b2;   // box bias (head)
  short* out_bf;     // extra: padded bf16 NHWC out
  float* out_f;      // head: packed d_out
  int M, Ci, iHp, iWp, Ho, Wo, Co;
  int S, kdim, stride, ioff;
  int oWp, onstride, oh;
  int mbox, row_base;
};

// --- 2-buffer, 1-barrier/K-step implicit-GEMM core (round-3 schedule) + T2 swizzle ---
// Schedule: stage(k+1) into buf^1 -> ds_read buf + MFMA -> __syncthreads (vmcnt0 drain
// + barrier: RAW for stage(k+1), WAR for buf reuse). Compiler-scheduled; no inline-asm
// waits (m131-m141/m232: hand-vmcnt at 4-wave 128² is null-to-negative).
// T2: global k-slot pre-XORed (LDS linear, rule #21), inverse XOR on ds_read.
template<int BM, int BN, bool HEAD>
__device__ __forceinline__ void conv_core(const ConvP p, int bx, int by) {
  constexpr int NA = BM / 64, NB = BN / 64, AM = BM / 32, AN = BN / 32;
  constexpr int ABUF = BM * 32, BBUF = BN * 32;
  __shared__ short As[2 * ABUF];
  __shared__ short Bs[2 * BBUF];
  const int t = threadIdx.x, lane = t & 63, wave = t >> 6;
  const int HW = p.Ho * p.Wo;
  const int sr = t >> 2;
  const int slot = ((t & 3) ^ ((t >> 3) & 3)) * 8;   // T2 pre-swizzled global k-slot

  const short* aBase[NA];
  const short* bBase[NB];
  #pragma unroll
  for (int i = 0; i < NA; ++i) {
    int pos = bx * BM + sr + i * 64; if (pos >= p.M) pos = p.M - 1;
    int n = pos / HW, rem = pos - n * HW;
    int yo = rem / p.Wo, xo = rem - yo * p.Wo;
    aBase[i] = p.in + ((size_t)(n * p.iHp + yo * p.stride + p.ioff) * p.iWp
                      + xo * p.stride + p.ioff) * p.Ci + slot;
  }
  #pragma unroll
  for (int i = 0; i < NB; ++i) {
    int co = by * BN + sr + i * 64; if (co >= p.Co) co = p.Co - 1;
    bBase[i] = p.w + (size_t)co * p.S * p.Ci + slot;
  }
  const int cs = p.Ci >> 5;          // 32-ci chunks per tap
  const int total = p.S * cs;

  auto stage = [&](int buf, int aoff, int boff) {
    #pragma unroll
    for (int i = 0; i < NA; ++i)
      gload16(aBase[i] + aoff, &As[buf * ABUF + i * 2048 + t * 8]);
    #pragma unroll
    for (int i = 0; i < NB; ++i)
      gload16(bBase[i] + boff, &Bs[buf * BBUF + i * 2048 + t * 8]);
  };

  int ntap = 0, ncc = 0;
  auto aoff_cur = [&]() -> int {
    if (p.S == 1) return ncc * 32;
    unsigned dy = (unsigned)ntap / 3u;
    int dx = ntap - (int)dy * 3;
    return ((int)dy * p.iWp + dx) * p.Ci + ncc * 32;
  };

  stage(0, aoff_cur(), 0);
  ++ncc; if (ncc == cs) { ncc = 0; ++ntap; }
  __syncthreads();                       // tile 0 landed

  f32x4 acc[AM][AN];
  #pragma unroll
  for (int i = 0; i < AM; ++i)
    #pragma unroll
    for (int j = 0; j < AN; ++j)
      acc[i][j] = (f32x4){0.f, 0.f, 0.f, 0.f};

  const int wr = (wave >> 1) * (BM / 2), wc = (wave & 1) * (BN / 2);
  const int lrow = lane & 15, lchunk = lane >> 4;

  int cur = 0;
  for (int ks = 0; ks < total; ++ks) {
    if (ks + 1 < total) {                // issue next tile's loads FIRST (overlap)
      stage(cur ^ 1, aoff_cur(), (ks + 1) * 32);
      ++ncc; if (ncc == cs) { ncc = 0; ++ntap; }
    }
    const short* aRd0 = &As[cur * ABUF];
    const short* bRd0 = &Bs[cur * BBUF];
    short8 a[AM], b[AN];
    #pragma unroll
    for (int i = 0; i < AM; ++i) {
      int r = wr + i * 16 + lrow;
      int ch = lchunk ^ ((r >> 1) & 3);  // T2 inverse swizzle on read
      a[i] = *reinterpret_cast<const short8*>(aRd0 + r * 32 + ch * 8);
    }
    #pragma unroll
    for (int j = 0; j < AN; ++j) {
      int r = wc + j * 16 + lrow;
      int ch = lchunk ^ ((r >> 1) & 3);
      b[j] = *reinterpret_cast<const short8*>(bRd0 + r * 32 + ch * 8);
    }
    #pragma unroll
    for (int i = 0; i < AM; ++i)
      #pragma unroll
      for (int j = 0; j < AN; ++j)
        acc[i][j] = __builtin_amdgcn_mfma_f32_16x16x32_bf16(a[i], b[j], acc[i][j], 0, 0, 0);
    __syncthreads();                     // drains vmcnt(0): next tile ready; reads of cur done
    cur ^= 1;
  }

  const int mk = p.mbox * 81;
  const int rb_ = (lane >> 4) * 4, cl_ = lane & 15;
  #pragma unroll
  for (int i = 0; i < AM; ++i)
    #pragma unroll
    for (int j = 0; j < AN; ++j)
      #pragma unroll
      for (int q = 0; q < 4; ++q) {
        int po = bx * BM + wr + i * 16 + rb_ + q;
        int co = by * BN + wc + j * 16 + cl_;
        if (po >= p.M || co >= p.Co) continue;
        float v = acc[i][j][q];
        if (!HEAD) {
          int n2 = po / HW, sp = po - n2 * HW;
          int y = sp / p.Wo, x = sp - y * p.Wo;
          float v2 = fmaxf(v + p.b1[co], 0.f);
          p.out_bf[((size_t)n2 * p.onstride + (y + p.oh) * p.oWp + (x + p.oh)) * p.Co + co] = f2bf(v2);
        } else {
          int n2 = po / HW, sp = po - n2 * HW;
          int mi, col; float bias;
          if (co < mk) { mi = co / 81; col = co - mi * 81; bias = p.b1[co]; }
          else { int cbx = co - mk; mi = cbx >> 2; col = 81 + (cbx & 3); bias = p.b2[cbx]; }
          size_t orow = (size_t)n2 * 8732 + p.row_base + (size_t)sp * p.mbox + mi;
          p.out_f[orow * 85 + col] = v + bias;
        }
      }
}

__global__ __launch_bounds__(256) void conv_tile64(ConvP p) {
  conv_core<64, 64, false>(p, blockIdx.x, blockIdx.y);
}

// ---------------- grouped head kernel (all 6 heads, one launch) ----------------------
struct HeadPack { ConvP L[6]; int blk0[6]; int nby[6]; };

__global__ __launch_bounds__(256) void head_grouped(HeadPack h, int nblk) {
  // T1: bijective chunked XCD swizzle (m204); logical order by-fast so an
  // A-panel's N-passes land on the same XCD's L2.
  int orig = blockIdx.x;
  int q = nblk >> 3, r = nblk & 7;
  int xcd = orig & 7, idx = orig >> 3;
  int wgid = (xcd < r ? xcd * (q + 1) : r * (q + 1) + (xcd - r) * q) + idx;
  int li = 0;
  #pragma unroll
  for (int i = 1; i < 6; ++i) if (wgid >= h.blk0[i]) li = i;
  int local = wgid - h.blk0[li];
  int by = local % h.nby[li];
  int bx = local / h.nby[li];
  conv_core<128, 128, true>(h.L[li], bx, by);
}

extern "C" void kernel_launch(void* const* d_in, const int* in_sizes, int n_in,
                              void* d_out, int out_size, void* d_ws, size_t ws_size,
                              hipStream_t stream) {
  const float* feat0 = (const float*)d_in[0];
  const float* feat1 = (const float*)d_in[1];
  const float* l2w   = (const float*)d_in[2];
  const float* ew[8]; const float* eb[8];
  for (int i = 0; i < 8; ++i) { ew[i] = (const float*)d_in[3 + 2 * i]; eb[i] = (const float*)d_in[4 + 2 * i]; }
  const float* cw[6]; const float* cb[6]; const float* bw[6]; const float* bb[6];
  for (int i = 0; i < 6; ++i) {
    cw[i] = (const float*)d_in[19 + 4 * i]; cb[i] = (const float*)d_in[20 + 4 * i];
    bw[i] = (const float*)d_in[21 + 4 * i]; bb[i] = (const float*)d_in[22 + 4 * i];
  }
  float* out = (float*)d_out;
  char* ws = (char*)d_ws;
  size_t off = 0;
  auto alloc = [&](size_t bytes) -> char* {
    char* p = ws + off;
    off = (off + bytes + 255) & ~(size_t)255;
    return p;
  };
  float* scale0 = (float*)alloc(23104 * 4);
  char* featStart = ws + off;
  short* f0b = (short*)alloc((size_t)16 * 40 * 40 * 512 * 2);   // 38x38, h=1
  short* f1b = (short*)alloc((size_t)16 * 21 * 21 * 1024 * 2);  // 19x19, h=1
  short* xe0 = (short*)alloc((size_t)16 * 21 * 21 * 256 * 2);   // 19x19, h=1
  short* f2b = (short*)alloc((size_t)16 * 12 * 12 * 512 * 2);   // 10x10, h=1
  short* xe2 = (short*)alloc((size_t)16 * 12 * 12 * 128 * 2);   // 10x10, h=1
  short* f3b = (short*)alloc((size_t)16 * 7 * 7 * 256 * 2);     // 5x5,  h=1
  short* xe4 = (short*)alloc((size_t)16 * 5 * 5 * 128 * 2);     // 5x5,  h=0
  short* f4b = (short*)alloc((size_t)16 * 5 * 5 * 256 * 2);     // 3x3,  h=1
  short* xe6 = (short*)alloc((size_t)16 * 3 * 3 * 128 * 2);     // 3x3,  h=0
  short* f5b = (short*)alloc((size_t)16 * 3 * 3 * 256 * 2);     // 1x1,  h=1
  size_t featBytes = (size_t)((ws + off) - featStart);

  static const int eCo[8] = {256, 512, 128, 256, 128, 256, 128, 256};
  static const int eCi[8] = {1024, 256, 512, 128, 256, 128, 256, 128};
  static const int eS[8]  = {1, 9, 1, 9, 1, 9, 1, 9};
  static const int mbox[6] = {4, 6, 6, 6, 4, 4};
  static const int hCi[6] = {512, 1024, 512, 256, 256, 256};

  WPrep wp; int total = 0; int segi = 0;
  short* ewb[8]; short* hwb[6];
  for (int i = 0; i < 8; ++i) {
    int e = eCo[i] * eCi[i] * eS[i];
    ewb[i] = (short*)alloc((size_t)e * 2);
    wp.seg[segi++] = {ew[i], ewb[i], eCi[i], eS[i], e};
    total += e;
  }
  for (int L = 0; L < 6; ++L) {
    int co = mbox[L] * 85;
    int e = co * hCi[L] * 9;
    hwb[L] = (short*)alloc((size_t)e * 2);
    int ecls = mbox[L] * 81 * hCi[L] * 9;
    wp.seg[segi++] = {cw[L], hwb[L], hCi[L], 9, ecls};
    wp.seg[segi++] = {bw[L], hwb[L] + (size_t)mbox[L] * 81 * 9 * hCi[L], hCi[L], 9, e - ecls};
    total += e;
  }

  hipMemsetAsync(featStart, 0, featBytes, stream);
  l2norm_kernel<<<dim3((23104 + 63) / 64), 256, 0, stream>>>(feat0, scale0, 512, 1444, 23104);
  to_nhwc_kernel<<<dim3(46, 16, 16), 256, 0, stream>>>(feat0, f0b, scale0, l2w, 512, 38, 38, 40, 1600, 1);
  to_nhwc_kernel<<<dim3(12, 32, 16), 256, 0, stream>>>(feat1, f1b, nullptr, nullptr, 1024, 19, 19, 21, 441, 1);
  wprep_kernel<<<dim3((total + 255) / 256), 256, 0, stream>>>(wp, total);

  auto mkP = [&](const short* in, const short* wbuf, const float* b1, const float* b2,
                 short* outb, float* outf, int Ci, int iHp, int iWp, int Ho, int Wo,
                 int Co, int S, int kd, int st, int ioff, int oWp, int onstride, int oh,
                 int m, int rb) {
    ConvP p{}; p.in = in; p.w = wbuf; p.b1 = b1; p.b2 = b2; p.out_bf = outb; p.out_f = outf;
    p.M = 16 * Ho * Wo; p.Ci = Ci; p.iHp = iHp; p.iWp = iWp; p.Ho = Ho; p.Wo = Wo; p.Co = Co;
    p.S = S; p.kdim = kd; p.stride = st; p.ioff = ioff;
    p.oWp = oWp; p.onstride = onstride; p.oh = oh; p.mbox = m; p.row_base = rb;
    return p;
  };
  auto run64 = [&](ConvP p) {
    conv_tile64<<<dim3((p.M + 63) / 64, (p.Co + 63) / 64), 256, 0, stream>>>(p);
  };

  // extras chain (2-phase pipelined 64x64, 16KB LDS)
  run64(mkP(f1b, ewb[0], eb[0], nullptr, xe0, nullptr, 1024, 21, 21, 19, 19, 256, 1, 1, 1, 1, 21, 441, 1, 0, 0));
  run64(mkP(xe0, ewb[1], eb[1], nullptr, f2b, nullptr,  256, 21, 21, 10, 10, 512, 9, 3, 2, 0, 12, 144, 1, 0, 0));
  run64(mkP(f2b, ewb[2], eb[2], nullptr, xe2, nullptr,  512, 12, 12, 10, 10, 128, 1, 1, 1, 1, 12, 144, 1, 0, 0));
  run64(mkP(xe2, ewb[3], eb[3], nullptr, f3b, nullptr,  128, 12, 12,  5,  5, 256, 9, 3, 2, 0,  7,  49, 1, 0, 0));
  run64(mkP(f3b, ewb[4], eb[4], nullptr, xe4, nullptr,  256,  7,  7,  5,  5, 128, 1, 1, 1, 1,  5,  25, 0, 0, 0));
  run64(mkP(xe4, ewb[5], eb[5], nullptr, f4b, nullptr,  128,  5,  5,  3,  3, 256, 9, 3, 1, 0,  5,  25, 1, 0, 0));
  run64(mkP(f4b, ewb[6], eb[6], nullptr, xe6, nullptr,  256,  5,  5,  3,  3, 128, 1, 1, 1, 1,  3,   9, 0, 0, 0));
  run64(mkP(xe6, ewb[7], eb[7], nullptr, f5b, nullptr,  128,  3,  3,  1,  1, 256, 9, 3, 1, 0,  3,   9, 1, 0, 0));

  // all 6 heads in ONE launch; longest-K layer (head1) first for tail balance
  HeadPack h;
  h.L[0] = mkP(f1b, hwb[1], cb[1], bb[1], nullptr, out, 1024, 21, 21, 19, 19, 6 * 85, 9, 3, 1, 0, 0, 0, 0, 6, 5776);
  h.L[1] = mkP(f0b, hwb[0], cb[0], bb[0], nullptr, out,  512, 40, 40, 38, 38, 4 * 85, 9, 3, 1, 0, 0, 0, 0, 4, 0);
  h.L[2] = mkP(f2b, hwb[2], cb[2], bb[2], nullptr, out,  512, 12, 12, 10, 10, 6 * 85, 9, 3, 1, 0, 0, 0, 0, 6, 7942);
  h.L[3] = mkP(f3b, hwb[3], cb[3], bb[3], nullptr, out,  256,  7,  7,  5,  5, 6 * 85, 9, 3, 1, 0, 0, 0, 0, 6, 8542);
  h.L[4] = mkP(f4b, hwb[4], cb[4], bb[4], nullptr, out,  256,  5,  5,  3,  3, 4 * 85, 9, 3, 1, 0, 0, 0, 0, 4, 8692);
  h.L[5] = mkP(f5b, hwb[5], cb[5], bb[5], nullptr, out,  256,  3,  3,  1,  1, 4 * 85, 9, 3, 1, 0, 0, 0, 0, 4, 8728);
  int nblk = 0;
  for (int i = 0; i < 6; ++i) {
    h.blk0[i] = nblk;
    int nbx = (h.L[i].M + 127) / 128;
    h.nby[i] = (h.L[i].Co + 127) / 128;
    nblk += nbx * h.nby[i];
  }
  head_grouped<<<dim3(nblk), 256, 0, stream>>>(h, nblk);
}

// Round 7
// 521.152 us; speedup vs baseline: 1.3836x; 1.3450x over previous
//
#include <hip/hip_runtime.h>
#include <hip/hip_bf16.h>

typedef __attribute__((ext_vector_type(8))) short short8;
typedef __attribute__((ext_vector_type(4))) float f32x4;

__device__ __forceinline__ short f2bf(float f) {
  unsigned u = __float_as_uint(f);
  u += 0x7fffu + ((u >> 16) & 1u);   // RNE
  return (short)(u >> 16);
}

__device__ __forceinline__ void gload16(const short* g, short* l) {
  __builtin_amdgcn_global_load_lds(
      (const __attribute__((address_space(1))) unsigned int*)g,
      (__attribute__((address_space(3))) unsigned int*)l, 16, 0, 0);
}

// ---------------- L2 norm scale ------------------------------------------------------
__global__ __launch_bounds__(256) void l2norm_kernel(const float* __restrict__ f0,
                                                     float* __restrict__ scale,
                                                     int C, int P, int total) {
  __shared__ float red[4][64];
  int pl = threadIdx.x & 63;
  int cg = threadIdx.x >> 6;
  int pos = blockIdx.x * 64 + pl;
  float s = 0.f;
  if (pos < total) {
    int n = pos / P, sp = pos - n * P;
    const float* base = f0 + (size_t)n * C * P + sp;
    int c0 = cg * (C >> 2), c1 = c0 + (C >> 2);
    for (int c = c0; c < c1; ++c) {
      float v = base[(size_t)c * P];
      s += v * v;
    }
  }
  red[cg][pl] = s;
  __syncthreads();
  if (threadIdx.x < 64 && pos < total) {
    float tot = red[0][pl] + red[1][pl] + red[2][pl] + red[3][pl];
    scale[pos] = 1.0f / (sqrtf(tot) + 1e-10f);
  }
}

// ------------- NCHW fp32 -> padded NHWC bf16 -----------------------------------------
__global__ __launch_bounds__(256) void to_nhwc_kernel(const float* __restrict__ src,
    short* __restrict__ dst, const float* __restrict__ rowscale,
    const float* __restrict__ chw, int C, int H, int W, int Wp, int nstride, int hh) {
  __shared__ float tile[32][33];
  int n = blockIdx.z;
  int P = H * W;
  int p0 = blockIdx.x * 32, c0 = blockIdx.y * 32;
  int tp = threadIdx.x & 31, tr = threadIdx.x >> 5;
  const float* s = src + (size_t)n * C * P;
  #pragma unroll
  for (int i = 0; i < 4; ++i) {
    int cl = tr + i * 8;
    int p = p0 + tp;
    tile[cl][tp] = (p < P) ? s[(size_t)(c0 + cl) * P + p] : 0.f;
  }
  __syncthreads();
  #pragma unroll
  for (int i = 0; i < 4; ++i) {
    int pl = tr + i * 8;
    int p = p0 + pl;
    if (p >= P) continue;
    int c = c0 + tp;
    float v = tile[tp][pl];
    if (chw)      v *= chw[c];
    if (rowscale) v *= rowscale[n * P + p];
    int y = p / W, x = p - y * W;
    dst[((size_t)n * nstride + (y + hh) * Wp + (x + hh)) * C + c] = f2bf(v);
  }
}

// ---------------- weight repack ------------------------------------------------------
struct WSeg { const float* src; short* dst; int Ci; int S; int elems; };
struct WPrep { WSeg seg[20]; };

__global__ __launch_bounds__(256) void wprep_kernel(WPrep p, int total) {
  int i = blockIdx.x * 256 + threadIdx.x;
  if (i >= total) return;
  int local = i;
  int si = 0;
  while (local >= p.seg[si].elems) { local -= p.seg[si].elems; ++si; }
  WSeg sg = p.seg[si];
  int ci = local % sg.Ci;
  int q  = local / sg.Ci;
  int s  = q % sg.S;
  int co = q / sg.S;
  float v = sg.src[((size_t)co * sg.Ci + ci) * sg.S + s];
  sg.dst[local] = f2bf(v);
}

// ---------------- conv params --------------------------------------------------------
struct ConvP {
  const short* in;   // bf16 padded NHWC [16][iHp][iWp][Ci]
  const short* w;    // bf16 [Co][S][Ci]
  const float* b1;   // bias (extra) / cls bias (head)
  const float* b2;   // box bias (head)
  short* out_bf;     // extra: padded bf16 NHWC out
  float* out_f;      // head: packed d_out
  int M, Ci, iHp, iWp, Ho, Wo, Co;
  int S, kdim, stride, ioff;
  int oWp, onstride, oh;
  int mbox, row_base;
};

// --- 2-buffer, 1-barrier/K-step implicit-GEMM core (round-3 schedule) + T2 swizzle ---
template<int BM, int BN, bool HEAD>
__device__ __forceinline__ void conv_core(const ConvP p, int bx, int by) {
  constexpr int NA = BM / 64, NB = BN / 64, AM = BM / 32, AN = BN / 32;
  constexpr int ABUF = BM * 32, BBUF = BN * 32;
  __shared__ short As[2 * ABUF];
  __shared__ short Bs[2 * BBUF];
  const int t = threadIdx.x, lane = t & 63, wave = t >> 6;
  const int HW = p.Ho * p.Wo;
  const int sr = t >> 2;
  const int slot = ((t & 3) ^ ((t >> 3) & 3)) * 8;   // T2 pre-swizzled global k-slot

  const short* aBase[NA];
  const short* bBase[NB];
  #pragma unroll
  for (int i = 0; i < NA; ++i) {
    int pos = bx * BM + sr + i * 64; if (pos >= p.M) pos = p.M - 1;
    int n = pos / HW, rem = pos - n * HW;
    int yo = rem / p.Wo, xo = rem - yo * p.Wo;
    aBase[i] = p.in + ((size_t)(n * p.iHp + yo * p.stride + p.ioff) * p.iWp
                      + xo * p.stride + p.ioff) * p.Ci + slot;
  }
  #pragma unroll
  for (int i = 0; i < NB; ++i) {
    int co = by * BN + sr + i * 64; if (co >= p.Co) co = p.Co - 1;
    bBase[i] = p.w + (size_t)co * p.S * p.Ci + slot;
  }
  const int cs = p.Ci >> 5;          // 32-ci chunks per tap
  const int total = p.S * cs;

  auto stage = [&](int buf, int aoff, int boff) {
    #pragma unroll
    for (int i = 0; i < NA; ++i)
      gload16(aBase[i] + aoff, &As[buf * ABUF + i * 2048 + t * 8]);
    #pragma unroll
    for (int i = 0; i < NB; ++i)
      gload16(bBase[i] + boff, &Bs[buf * BBUF + i * 2048 + t * 8]);
  };

  int ntap = 0, ncc = 0;
  auto aoff_cur = [&]() -> int {
    if (p.S == 1) return ncc * 32;
    unsigned dy = (unsigned)ntap / 3u;
    int dx = ntap - (int)dy * 3;
    return ((int)dy * p.iWp + dx) * p.Ci + ncc * 32;
  };

  stage(0, aoff_cur(), 0);
  ++ncc; if (ncc == cs) { ncc = 0; ++ntap; }
  __syncthreads();                       // tile 0 landed

  f32x4 acc[AM][AN];
  #pragma unroll
  for (int i = 0; i < AM; ++i)
    #pragma unroll
    for (int j = 0; j < AN; ++j)
      acc[i][j] = (f32x4){0.f, 0.f, 0.f, 0.f};

  const int wr = (wave >> 1) * (BM / 2), wc = (wave & 1) * (BN / 2);
  const int lrow = lane & 15, lchunk = lane >> 4;

  int cur = 0;
  for (int ks = 0; ks < total; ++ks) {
    if (ks + 1 < total) {                // issue next tile's loads FIRST (overlap)
      stage(cur ^ 1, aoff_cur(), (ks + 1) * 32);
      ++ncc; if (ncc == cs) { ncc = 0; ++ntap; }
    }
    const short* aRd0 = &As[cur * ABUF];
    const short* bRd0 = &Bs[cur * BBUF];
    short8 a[AM], b[AN];
    #pragma unroll
    for (int i = 0; i < AM; ++i) {
      int r = wr + i * 16 + lrow;
      int ch = lchunk ^ ((r >> 1) & 3);  // T2 inverse swizzle on read
      a[i] = *reinterpret_cast<const short8*>(aRd0 + r * 32 + ch * 8);
    }
    #pragma unroll
    for (int j = 0; j < AN; ++j) {
      int r = wc + j * 16 + lrow;
      int ch = lchunk ^ ((r >> 1) & 3);
      b[j] = *reinterpret_cast<const short8*>(bRd0 + r * 32 + ch * 8);
    }
    #pragma unroll
    for (int i = 0; i < AM; ++i)
      #pragma unroll
      for (int j = 0; j < AN; ++j)
        acc[i][j] = __builtin_amdgcn_mfma_f32_16x16x32_bf16(a[i], b[j], acc[i][j], 0, 0, 0);
    __syncthreads();                     // drains vmcnt(0): next tile ready; reads of cur done
    cur ^= 1;
  }

  const int mk = p.mbox * 81;
  const int rb_ = (lane >> 4) * 4, cl_ = lane & 15;
  #pragma unroll
  for (int i = 0; i < AM; ++i)
    #pragma unroll
    for (int j = 0; j < AN; ++j)
      #pragma unroll
      for (int q = 0; q < 4; ++q) {
        int po = bx * BM + wr + i * 16 + rb_ + q;
        int co = by * BN + wc + j * 16 + cl_;
        if (po >= p.M || co >= p.Co) continue;
        float v = acc[i][j][q];
        if (!HEAD) {
          int n2 = po / HW, sp = po - n2 * HW;
          int y = sp / p.Wo, x = sp - y * p.Wo;
          float v2 = fmaxf(v + p.b1[co], 0.f);
          p.out_bf[((size_t)n2 * p.onstride + (y + p.oh) * p.oWp + (x + p.oh)) * p.Co + co] = f2bf(v2);
        } else {
          int n2 = po / HW, sp = po - n2 * HW;
          int mi, col; float bias;
          if (co < mk) { mi = co / 81; col = co - mi * 81; bias = p.b1[co]; }
          else { int cbx = co - mk; mi = cbx >> 2; col = 81 + (cbx & 3); bias = p.b2[cbx]; }
          size_t orow = (size_t)n2 * 8732 + p.row_base + (size_t)sp * p.mbox + mi;
          p.out_f[orow * 85 + col] = v + bias;
        }
      }
}

__global__ __launch_bounds__(256) void conv_tile64(ConvP p) {
  conv_core<64, 64, false>(p, blockIdx.x, blockIdx.y);
}

// ------ grouped head kernel: group-preserving, round-robin-balanced XCD mapping ------
// Reuse unit = group (layer, bx) with nby member blocks sharing one A-panel. Hardware
// maps physical block p -> XCD p&7. Groups assigned round-robin (gid%8 -> XCD), so
// each XCD receives a proportional mix of long-K and short-K groups (load balance),
// while a group's members occupy consecutive slots of ONE XCD (L2 locality).
// sb[li*8+x] = first within-XCD slot of layer li on XCD x (host-precomputed).
struct HeadPack { ConvP L[6]; int g0[6]; int nbyA[6]; int sb[56]; };

__global__ __launch_bounds__(256) void head_grouped(HeadPack h) {
  int p = blockIdx.x, x = p & 7, s = p >> 3;
  if (s >= h.sb[48 + x]) return;         // padding block
  int li = 0;
  #pragma unroll
  for (int i = 1; i < 6; ++i) if (s >= h.sb[i * 8 + x]) li = i;
  int r = s - h.sb[li * 8 + x];
  int nby = h.nbyA[li];
  int k = r / nby, by = r - k * nby;
  int bx = ((x - h.g0[li]) & 7) + 8 * k; // bx of the k-th group of layer li on XCD x
  conv_core<128, 128, true>(h.L[li], bx, by);
}

extern "C" void kernel_launch(void* const* d_in, const int* in_sizes, int n_in,
                              void* d_out, int out_size, void* d_ws, size_t ws_size,
                              hipStream_t stream) {
  const float* feat0 = (const float*)d_in[0];
  const float* feat1 = (const float*)d_in[1];
  const float* l2w   = (const float*)d_in[2];
  const float* ew[8]; const float* eb[8];
  for (int i = 0; i < 8; ++i) { ew[i] = (const float*)d_in[3 + 2 * i]; eb[i] = (const float*)d_in[4 + 2 * i]; }
  const float* cw[6]; const float* cb[6]; const float* bw[6]; const float* bb[6];
  for (int i = 0; i < 6; ++i) {
    cw[i] = (const float*)d_in[19 + 4 * i]; cb[i] = (const float*)d_in[20 + 4 * i];
    bw[i] = (const float*)d_in[21 + 4 * i]; bb[i] = (const float*)d_in[22 + 4 * i];
  }
  float* out = (float*)d_out;
  char* ws = (char*)d_ws;
  size_t off = 0;
  auto alloc = [&](size_t bytes) -> char* {
    char* p = ws + off;
    off = (off + bytes + 255) & ~(size_t)255;
    return p;
  };
  float* scale0 = (float*)alloc(23104 * 4);
  char* featStart = ws + off;
  short* f0b = (short*)alloc((size_t)16 * 40 * 40 * 512 * 2);   // 38x38, h=1
  short* f1b = (short*)alloc((size_t)16 * 21 * 21 * 1024 * 2);  // 19x19, h=1
  short* xe0 = (short*)alloc((size_t)16 * 21 * 21 * 256 * 2);   // 19x19, h=1
  short* f2b = (short*)alloc((size_t)16 * 12 * 12 * 512 * 2);   // 10x10, h=1
  short* xe2 = (short*)alloc((size_t)16 * 12 * 12 * 128 * 2);   // 10x10, h=1
  short* f3b = (short*)alloc((size_t)16 * 7 * 7 * 256 * 2);     // 5x5,  h=1
  short* xe4 = (short*)alloc((size_t)16 * 5 * 5 * 128 * 2);     // 5x5,  h=0
  short* f4b = (short*)alloc((size_t)16 * 5 * 5 * 256 * 2);     // 3x3,  h=1
  short* xe6 = (short*)alloc((size_t)16 * 3 * 3 * 128 * 2);     // 3x3,  h=0
  short* f5b = (short*)alloc((size_t)16 * 3 * 3 * 256 * 2);     // 1x1,  h=1
  size_t featBytes = (size_t)((ws + off) - featStart);

  static const int eCo[8] = {256, 512, 128, 256, 128, 256, 128, 256};
  static const int eCi[8] = {1024, 256, 512, 128, 256, 128, 256, 128};
  static const int eS[8]  = {1, 9, 1, 9, 1, 9, 1, 9};
  static const int mbox[6] = {4, 6, 6, 6, 4, 4};
  static const int hCi[6] = {512, 1024, 512, 256, 256, 256};

  WPrep wp; int total = 0; int segi = 0;
  short* ewb[8]; short* hwb[6];
  for (int i = 0; i < 8; ++i) {
    int e = eCo[i] * eCi[i] * eS[i];
    ewb[i] = (short*)alloc((size_t)e * 2);
    wp.seg[segi++] = {ew[i], ewb[i], eCi[i], eS[i], e};
    total += e;
  }
  for (int L = 0; L < 6; ++L) {
    int co = mbox[L] * 85;
    int e = co * hCi[L] * 9;
    hwb[L] = (short*)alloc((size_t)e * 2);
    int ecls = mbox[L] * 81 * hCi[L] * 9;
    wp.seg[segi++] = {cw[L], hwb[L], hCi[L], 9, ecls};
    wp.seg[segi++] = {bw[L], hwb[L] + (size_t)mbox[L] * 81 * 9 * hCi[L], hCi[L], 9, e - ecls};
    total += e;
  }

  hipMemsetAsync(featStart, 0, featBytes, stream);
  l2norm_kernel<<<dim3((23104 + 63) / 64), 256, 0, stream>>>(feat0, scale0, 512, 1444, 23104);
  to_nhwc_kernel<<<dim3(46, 16, 16), 256, 0, stream>>>(feat0, f0b, scale0, l2w, 512, 38, 38, 40, 1600, 1);
  to_nhwc_kernel<<<dim3(12, 32, 16), 256, 0, stream>>>(feat1, f1b, nullptr, nullptr, 1024, 19, 19, 21, 441, 1);
  wprep_kernel<<<dim3((total + 255) / 256), 256, 0, stream>>>(wp, total);

  auto mkP = [&](const short* in, const short* wbuf, const float* b1, const float* b2,
                 short* outb, float* outf, int Ci, int iHp, int iWp, int Ho, int Wo,
                 int Co, int S, int kd, int st, int ioff, int oWp, int onstride, int oh,
                 int m, int rb) {
    ConvP p{}; p.in = in; p.w = wbuf; p.b1 = b1; p.b2 = b2; p.out_bf = outb; p.out_f = outf;
    p.M = 16 * Ho * Wo; p.Ci = Ci; p.iHp = iHp; p.iWp = iWp; p.Ho = Ho; p.Wo = Wo; p.Co = Co;
    p.S = S; p.kdim = kd; p.stride = st; p.ioff = ioff;
    p.oWp = oWp; p.onstride = onstride; p.oh = oh; p.mbox = m; p.row_base = rb;
    return p;
  };
  auto run64 = [&](ConvP p) {
    conv_tile64<<<dim3((p.M + 63) / 64, (p.Co + 63) / 64), 256, 0, stream>>>(p);
  };

  // extras chain (2-phase pipelined 64x64, 16KB LDS)
  run64(mkP(f1b, ewb[0], eb[0], nullptr, xe0, nullptr, 1024, 21, 21, 19, 19, 256, 1, 1, 1, 1, 21, 441, 1, 0, 0));
  run64(mkP(xe0, ewb[1], eb[1], nullptr, f2b, nullptr,  256, 21, 21, 10, 10, 512, 9, 3, 2, 0, 12, 144, 1, 0, 0));
  run64(mkP(f2b, ewb[2], eb[2], nullptr, xe2, nullptr,  512, 12, 12, 10, 10, 128, 1, 1, 1, 1, 12, 144, 1, 0, 0));
  run64(mkP(xe2, ewb[3], eb[3], nullptr, f3b, nullptr,  128, 12, 12,  5,  5, 256, 9, 3, 2, 0,  7,  49, 1, 0, 0));
  run64(mkP(f3b, ewb[4], eb[4], nullptr, xe4, nullptr,  256,  7,  7,  5,  5, 128, 1, 1, 1, 1,  5,  25, 0, 0, 0));
  run64(mkP(xe4, ewb[5], eb[5], nullptr, f4b, nullptr,  128,  5,  5,  3,  3, 256, 9, 3, 1, 0,  5,  25, 1, 0, 0));
  run64(mkP(f4b, ewb[6], eb[6], nullptr, xe6, nullptr,  256,  5,  5,  3,  3, 128, 1, 1, 1, 1,  3,   9, 0, 0, 0));
  run64(mkP(xe6, ewb[7], eb[7], nullptr, f5b, nullptr,  128,  3,  3,  1,  1, 256, 9, 3, 1, 0,  3,   9, 1, 0, 0));

  // all 6 heads in ONE launch (long-K head1 first in group enumeration)
  HeadPack h;
  h.L[0] = mkP(f1b, hwb[1], cb[1], bb[1], nullptr, out, 1024, 21, 21, 19, 19, 6 * 85, 9, 3, 1, 0, 0, 0, 0, 6, 5776);
  h.L[1] = mkP(f0b, hwb[0], cb[0], bb[0], nullptr, out,  512, 40, 40, 38, 38, 4 * 85, 9, 3, 1, 0, 0, 0, 0, 4, 0);
  h.L[2] = mkP(f2b, hwb[2], cb[2], bb[2], nullptr, out,  512, 12, 12, 10, 10, 6 * 85, 9, 3, 1, 0, 0, 0, 0, 6, 7942);
  h.L[3] = mkP(f3b, hwb[3], cb[3], bb[3], nullptr, out,  256,  7,  7,  5,  5, 6 * 85, 9, 3, 1, 0, 0, 0, 0, 6, 8542);
  h.L[4] = mkP(f4b, hwb[4], cb[4], bb[4], nullptr, out,  256,  5,  5,  3,  3, 4 * 85, 9, 3, 1, 0, 0, 0, 0, 4, 8692);
  h.L[5] = mkP(f5b, hwb[5], cb[5], bb[5], nullptr, out,  256,  3,  3,  1,  1, 4 * 85, 9, 3, 1, 0, 0, 0, 0, 4, 8728);

  // host precompute: per-layer, per-XCD slot bases for the balanced group mapping
  int gid = 0;
  for (int li = 0; li < 6; ++li) {
    int nbx = (h.L[li].M + 127) / 128;
    h.nbyA[li] = (h.L[li].Co + 127) / 128;
    h.g0[li] = gid;
    for (int x = 0; x < 8; ++x) {
      int base = (li == 0) ? 0 : h.sb[(li - 1) * 8 + 8 + x - 8];   // sb[li*8+x] set below
    }
    gid += nbx;
  }
  // fill sb properly (sb[li*8+x] = start slot of layer li on XCD x)
  for (int x = 0; x < 8; ++x) h.sb[x] = 0;
  gid = 0;
  for (int li = 0; li < 6; ++li) {
    int nbx = (h.L[li].M + 127) / 128;
    for (int x = 0; x < 8; ++x) {
      int f = ((x - gid) % 8 + 8) % 8;                  // first group offset on XCD x
      int cnt = (f < nbx) ? (nbx - f + 7) / 8 : 0;      // groups of this layer on XCD x
      h.sb[(li + 1) * 8 + x] = h.sb[li * 8 + x] + h.nbyA[li] * cnt;
    }
    gid += nbx;
  }
  int maxSlots = 0;
  for (int x = 0; x < 8; ++x) if (h.sb[48 + x] > maxSlots) maxSlots = h.sb[48 + x];
  head_grouped<<<dim3(8 * maxSlots), 256, 0, stream>>>(h);
}

// Round 8
// 440.459 us; speedup vs baseline: 1.6371x; 1.1832x over previous
//
#include <hip/hip_runtime.h>
#include <hip/hip_bf16.h>

typedef __attribute__((ext_vector_type(8))) short short8;
typedef __attribute__((ext_vector_type(4))) float f32x4;

__device__ __forceinline__ short f2bf(float f) {
  unsigned u = __float_as_uint(f);
  u += 0x7fffu + ((u >> 16) & 1u);   // RNE
  return (short)(u >> 16);
}

__device__ __forceinline__ void gload16(const short* g, short* l) {
  __builtin_amdgcn_global_load_lds(
      (const __attribute__((address_space(1))) unsigned int*)g,
      (__attribute__((address_space(3))) unsigned int*)l, 16, 0, 0);
}

// ---------------- L2 norm scale ------------------------------------------------------
__global__ __launch_bounds__(256) void l2norm_kernel(const float* __restrict__ f0,
                                                     float* __restrict__ scale,
                                                     int C, int P, int total) {
  __shared__ float red[4][64];
  int pl = threadIdx.x & 63;
  int cg = threadIdx.x >> 6;
  int pos = blockIdx.x * 64 + pl;
  float s = 0.f;
  if (pos < total) {
    int n = pos / P, sp = pos - n * P;
    const float* base = f0 + (size_t)n * C * P + sp;
    int c0 = cg * (C >> 2), c1 = c0 + (C >> 2);
    for (int c = c0; c < c1; ++c) {
      float v = base[(size_t)c * P];
      s += v * v;
    }
  }
  red[cg][pl] = s;
  __syncthreads();
  if (threadIdx.x < 64 && pos < total) {
    float tot = red[0][pl] + red[1][pl] + red[2][pl] + red[3][pl];
    scale[pos] = 1.0f / (sqrtf(tot) + 1e-10f);
  }
}

// ------------- NCHW fp32 -> padded NHWC bf16 -----------------------------------------
__global__ __launch_bounds__(256) void to_nhwc_kernel(const float* __restrict__ src,
    short* __restrict__ dst, const float* __restrict__ rowscale,
    const float* __restrict__ chw, int C, int H, int W, int Wp, int nstride, int hh) {
  __shared__ float tile[32][33];
  int n = blockIdx.z;
  int P = H * W;
  int p0 = blockIdx.x * 32, c0 = blockIdx.y * 32;
  int tp = threadIdx.x & 31, tr = threadIdx.x >> 5;
  const float* s = src + (size_t)n * C * P;
  #pragma unroll
  for (int i = 0; i < 4; ++i) {
    int cl = tr + i * 8;
    int p = p0 + tp;
    tile[cl][tp] = (p < P) ? s[(size_t)(c0 + cl) * P + p] : 0.f;
  }
  __syncthreads();
  #pragma unroll
  for (int i = 0; i < 4; ++i) {
    int pl = tr + i * 8;
    int p = p0 + pl;
    if (p >= P) continue;
    int c = c0 + tp;
    float v = tile[tp][pl];
    if (chw)      v *= chw[c];
    if (rowscale) v *= rowscale[n * P + p];
    int y = p / W, x = p - y * W;
    dst[((size_t)n * nstride + (y + hh) * Wp + (x + hh)) * C + c] = f2bf(v);
  }
}

// ---------------- weight repack ------------------------------------------------------
struct WSeg { const float* src; short* dst; int Ci; int S; int elems; };
struct WPrep { WSeg seg[20]; };

__global__ __launch_bounds__(256) void wprep_kernel(WPrep p, int total) {
  int i = blockIdx.x * 256 + threadIdx.x;
  if (i >= total) return;
  int local = i;
  int si = 0;
  while (local >= p.seg[si].elems) { local -= p.seg[si].elems; ++si; }
  WSeg sg = p.seg[si];
  int ci = local % sg.Ci;
  int q  = local / sg.Ci;
  int s  = q % sg.S;
  int co = q / sg.S;
  float v = sg.src[((size_t)co * sg.Ci + ci) * sg.S + s];
  sg.dst[local] = f2bf(v);
}

// ---------------- conv params --------------------------------------------------------
struct ConvP {
  const short* in;   // bf16 padded NHWC [16][iHp][iWp][Ci]
  const short* w;    // bf16 [Co][S][Ci]
  const float* b1;   // bias (extra) / cls bias (head)
  const float* b2;   // box bias (head)
  short* out_bf;     // extra: padded bf16 NHWC out
  float* out_f;      // head: packed d_out
  int M, Ci, iHp, iWp, Ho, Wo, Co;
  int S, kdim, stride, ioff;
  int oWp, onstride, oh;
  int mbox, row_base;
};

// --- BK=64, 2-buffer, 1-barrier/K-step implicit-GEMM core + swizzle ------------------
// Per K-step: stage(k+1) into buf^1 (8 gload_lds) -> ds_read buf (16 b128) -> 32 MFMA
// -> __syncthreads (vmcnt0 drain = RAW for k+1, WAR for buf). BK=64 halves barrier
// count vs BK=32 (latency amortization); hand-vmcnt variants regress here (r4/r5,m232).
// Swizzle (rule #21 both-sides): global slot (t&7)^((t>>3)&7) staged to linear LDS;
// read chunk ((lane>>4)|(kk<<2))^(r&7). Each wave b128 read covers all 32 banks x8
// (structural minimum) -> conflict-free.
template<int BM, int BN, bool HEAD>
__device__ __forceinline__ void conv_core(const ConvP p, int bx, int by) {
  constexpr int NRA = BM / 32, NRB = BN / 32;      // staging row-groups of 32
  constexpr int AM = BM / 32, AN = BN / 32;        // MFMA frag rows/cols per wave
  constexpr int ABUF = BM * 64, BBUF = BN * 64;    // shorts per buffer
  __shared__ short As[2 * ABUF];
  __shared__ short Bs[2 * BBUF];
  const int t = threadIdx.x, lane = t & 63, wave = t >> 6;
  const int HW = p.Ho * p.Wo;
  const int sr = t >> 3;                           // 0..31
  const int slot = ((t & 7) ^ (sr & 7)) * 8;       // pre-swizzled global k-slot (shorts)

  const short* aBase[NRA];
  const short* bBase[NRB];
  #pragma unroll
  for (int i = 0; i < NRA; ++i) {
    int pos = bx * BM + sr + i * 32; if (pos >= p.M) pos = p.M - 1;
    int n = pos / HW, rem = pos - n * HW;
    int yo = rem / p.Wo, xo = rem - yo * p.Wo;
    aBase[i] = p.in + ((size_t)(n * p.iHp + yo * p.stride + p.ioff) * p.iWp
                      + xo * p.stride + p.ioff) * p.Ci + slot;
  }
  #pragma unroll
  for (int i = 0; i < NRB; ++i) {
    int co = by * BN + sr + i * 32; if (co >= p.Co) co = p.Co - 1;
    bBase[i] = p.w + (size_t)co * p.S * p.Ci + slot;
  }
  const int cs = p.Ci >> 6;          // 64-ci chunks per tap (>=1, power of 2)
  const int total = p.S * cs;

  auto stage = [&](int buf, int aoff, int boff) {
    #pragma unroll
    for (int i = 0; i < NRA; ++i)
      gload16(aBase[i] + aoff, &As[buf * ABUF + i * 2048 + t * 8]);
    #pragma unroll
    for (int i = 0; i < NRB; ++i)
      gload16(bBase[i] + boff, &Bs[buf * BBUF + i * 2048 + t * 8]);
  };

  int ntap = 0, ncc = 0;
  auto aoff_cur = [&]() -> int {
    if (p.S == 1) return ncc * 64;
    unsigned dy = (unsigned)ntap / 3u;
    int dx = ntap - (int)dy * 3;
    return ((int)dy * p.iWp + dx) * p.Ci + ncc * 64;
  };

  stage(0, aoff_cur(), 0);
  ++ncc; if (ncc == cs) { ncc = 0; ++ntap; }
  __syncthreads();                       // tile 0 landed

  f32x4 acc[AM][AN];
  #pragma unroll
  for (int i = 0; i < AM; ++i)
    #pragma unroll
    for (int j = 0; j < AN; ++j)
      acc[i][j] = (f32x4){0.f, 0.f, 0.f, 0.f};

  const int wr = (wave >> 1) * (BM / 2), wc = (wave & 1) * (BN / 2);
  const int lrow = lane & 15, kgrp = lane >> 4;

  int cur = 0;
  for (int ks = 0; ks < total; ++ks) {
    if (ks + 1 < total) {                // issue next tile's loads FIRST (overlap)
      stage(cur ^ 1, aoff_cur(), (ks + 1) * 64);
      ++ncc; if (ncc == cs) { ncc = 0; ++ntap; }
    }
    const short* aRd0 = &As[cur * ABUF];
    const short* bRd0 = &Bs[cur * BBUF];
    short8 a[AM][2], b[AN][2];
    #pragma unroll
    for (int i = 0; i < AM; ++i) {
      int r = wr + i * 16 + lrow;
      #pragma unroll
      for (int kk = 0; kk < 2; ++kk) {
        int ch = (kgrp | (kk << 2)) ^ (r & 7);
        a[i][kk] = *reinterpret_cast<const short8*>(aRd0 + r * 64 + ch * 8);
      }
    }
    #pragma unroll
    for (int j = 0; j < AN; ++j) {
      int r = wc + j * 16 + lrow;
      #pragma unroll
      for (int kk = 0; kk < 2; ++kk) {
        int ch = (kgrp | (kk << 2)) ^ (r & 7);
        b[j][kk] = *reinterpret_cast<const short8*>(bRd0 + r * 64 + ch * 8);
      }
    }
    #pragma unroll
    for (int kk = 0; kk < 2; ++kk)
      #pragma unroll
      for (int i = 0; i < AM; ++i)
        #pragma unroll
        for (int j = 0; j < AN; ++j)
          acc[i][j] = __builtin_amdgcn_mfma_f32_16x16x32_bf16(a[i][kk], b[j][kk], acc[i][j], 0, 0, 0);
    __syncthreads();                     // drains vmcnt(0): next tile ready; reads done
    cur ^= 1;
  }

  const int mk = p.mbox * 81;
  const int rb_ = (lane >> 4) * 4, cl_ = lane & 15;
  #pragma unroll
  for (int i = 0; i < AM; ++i)
    #pragma unroll
    for (int j = 0; j < AN; ++j)
      #pragma unroll
      for (int q = 0; q < 4; ++q) {
        int po = bx * BM + wr + i * 16 + rb_ + q;
        int co = by * BN + wc + j * 16 + cl_;
        if (po >= p.M || co >= p.Co) continue;
        float v = acc[i][j][q];
        if (!HEAD) {
          int n2 = po / HW, sp = po - n2 * HW;
          int y = sp / p.Wo, x = sp - y * p.Wo;
          float v2 = fmaxf(v + p.b1[co], 0.f);
          p.out_bf[((size_t)n2 * p.onstride + (y + p.oh) * p.oWp + (x + p.oh)) * p.Co + co] = f2bf(v2);
        } else {
          int n2 = po / HW, sp = po - n2 * HW;
          int mi, col; float bias;
          if (co < mk) { mi = co / 81; col = co - mi * 81; bias = p.b1[co]; }
          else { int cbx = co - mk; mi = cbx >> 2; col = 81 + (cbx & 3); bias = p.b2[cbx]; }
          size_t orow = (size_t)n2 * 8732 + p.row_base + (size_t)sp * p.mbox + mi;
          p.out_f[orow * 85 + col] = v + bias;
        }
      }
}

__global__ __launch_bounds__(256) void conv_tile64(ConvP p) {
  conv_core<64, 64, false>(p, blockIdx.x, blockIdx.y);
}

// ------ grouped head kernel: group-preserving, round-robin-balanced XCD mapping ------
// Reuse unit = group (layer, bx) with nby member blocks sharing one A-panel. Hardware
// maps physical block p -> XCD p&7. Groups assigned round-robin (gid%8 -> XCD) so each
// XCD gets a proportional mix of long-K and short-K groups; a group's members occupy
// consecutive slots of ONE XCD. sb[li*8+x] = first slot of layer li on XCD x.
struct HeadPack { ConvP L[6]; int g0[6]; int nbyA[6]; int sb[56]; };

__global__ __launch_bounds__(256) void head_grouped(HeadPack h) {
  int p = blockIdx.x, x = p & 7, s = p >> 3;
  if (s >= h.sb[48 + x]) return;         // padding block
  int li = 0;
  #pragma unroll
  for (int i = 1; i < 6; ++i) if (s >= h.sb[i * 8 + x]) li = i;
  int r = s - h.sb[li * 8 + x];
  int nby = h.nbyA[li];
  int k = r / nby, by = r - k * nby;
  int bx = ((x - h.g0[li]) & 7) + 8 * k; // bx of the k-th group of layer li on XCD x
  conv_core<128, 128, true>(h.L[li], bx, by);
}

extern "C" void kernel_launch(void* const* d_in, const int* in_sizes, int n_in,
                              void* d_out, int out_size, void* d_ws, size_t ws_size,
                              hipStream_t stream) {
  const float* feat0 = (const float*)d_in[0];
  const float* feat1 = (const float*)d_in[1];
  const float* l2w   = (const float*)d_in[2];
  const float* ew[8]; const float* eb[8];
  for (int i = 0; i < 8; ++i) { ew[i] = (const float*)d_in[3 + 2 * i]; eb[i] = (const float*)d_in[4 + 2 * i]; }
  const float* cw[6]; const float* cb[6]; const float* bw[6]; const float* bb[6];
  for (int i = 0; i < 6; ++i) {
    cw[i] = (const float*)d_in[19 + 4 * i]; cb[i] = (const float*)d_in[20 + 4 * i];
    bw[i] = (const float*)d_in[21 + 4 * i]; bb[i] = (const float*)d_in[22 + 4 * i];
  }
  float* out = (float*)d_out;
  char* ws = (char*)d_ws;
  size_t off = 0;
  auto alloc = [&](size_t bytes) -> char* {
    char* p = ws + off;
    off = (off + bytes + 255) & ~(size_t)255;
    return p;
  };
  float* scale0 = (float*)alloc(23104 * 4);
  char* featStart = ws + off;
  short* f0b = (short*)alloc((size_t)16 * 40 * 40 * 512 * 2);   // 38x38, h=1
  short* f1b = (short*)alloc((size_t)16 * 21 * 21 * 1024 * 2);  // 19x19, h=1
  short* xe0 = (short*)alloc((size_t)16 * 21 * 21 * 256 * 2);   // 19x19, h=1
  short* f2b = (short*)alloc((size_t)16 * 12 * 12 * 512 * 2);   // 10x10, h=1
  short* xe2 = (short*)alloc((size_t)16 * 12 * 12 * 128 * 2);   // 10x10, h=1
  short* f3b = (short*)alloc((size_t)16 * 7 * 7 * 256 * 2);     // 5x5,  h=1
  short* xe4 = (short*)alloc((size_t)16 * 5 * 5 * 128 * 2);     // 5x5,  h=0
  short* f4b = (short*)alloc((size_t)16 * 5 * 5 * 256 * 2);     // 3x3,  h=1
  short* xe6 = (short*)alloc((size_t)16 * 3 * 3 * 128 * 2);     // 3x3,  h=0
  short* f5b = (short*)alloc((size_t)16 * 3 * 3 * 256 * 2);     // 1x1,  h=1
  size_t featBytes = (size_t)((ws + off) - featStart);

  static const int eCo[8] = {256, 512, 128, 256, 128, 256, 128, 256};
  static const int eCi[8] = {1024, 256, 512, 128, 256, 128, 256, 128};
  static const int eS[8]  = {1, 9, 1, 9, 1, 9, 1, 9};
  static const int mbox[6] = {4, 6, 6, 6, 4, 4};
  static const int hCi[6] = {512, 1024, 512, 256, 256, 256};

  WPrep wp; int total = 0; int segi = 0;
  short* ewb[8]; short* hwb[6];
  for (int i = 0; i < 8; ++i) {
    int e = eCo[i] * eCi[i] * eS[i];
    ewb[i] = (short*)alloc((size_t)e * 2);
    wp.seg[segi++] = {ew[i], ewb[i], eCi[i], eS[i], e};
    total += e;
  }
  for (int L = 0; L < 6; ++L) {
    int co = mbox[L] * 85;
    int e = co * hCi[L] * 9;
    hwb[L] = (short*)alloc((size_t)e * 2);
    int ecls = mbox[L] * 81 * hCi[L] * 9;
    wp.seg[segi++] = {cw[L], hwb[L], hCi[L], 9, ecls};
    wp.seg[segi++] = {bw[L], hwb[L] + (size_t)mbox[L] * 81 * 9 * hCi[L], hCi[L], 9, e - ecls};
    total += e;
  }

  hipMemsetAsync(featStart, 0, featBytes, stream);
  l2norm_kernel<<<dim3((23104 + 63) / 64), 256, 0, stream>>>(feat0, scale0, 512, 1444, 23104);
  to_nhwc_kernel<<<dim3(46, 16, 16), 256, 0, stream>>>(feat0, f0b, scale0, l2w, 512, 38, 38, 40, 1600, 1);
  to_nhwc_kernel<<<dim3(12, 32, 16), 256, 0, stream>>>(feat1, f1b, nullptr, nullptr, 1024, 19, 19, 21, 441, 1);
  wprep_kernel<<<dim3((total + 255) / 256), 256, 0, stream>>>(wp, total);

  auto mkP = [&](const short* in, const short* wbuf, const float* b1, const float* b2,
                 short* outb, float* outf, int Ci, int iHp, int iWp, int Ho, int Wo,
                 int Co, int S, int kd, int st, int ioff, int oWp, int onstride, int oh,
                 int m, int rb) {
    ConvP p{}; p.in = in; p.w = wbuf; p.b1 = b1; p.b2 = b2; p.out_bf = outb; p.out_f = outf;
    p.M = 16 * Ho * Wo; p.Ci = Ci; p.iHp = iHp; p.iWp = iWp; p.Ho = Ho; p.Wo = Wo; p.Co = Co;
    p.S = S; p.kdim = kd; p.stride = st; p.ioff = ioff;
    p.oWp = oWp; p.onstride = onstride; p.oh = oh; p.mbox = m; p.row_base = rb;
    return p;
  };
  auto run64 = [&](ConvP p) {
    conv_tile64<<<dim3((p.M + 63) / 64, (p.Co + 63) / 64), 256, 0, stream>>>(p);
  };

  // extras chain (BK=64 pipelined 64x64, 32KB LDS)
  run64(mkP(f1b, ewb[0], eb[0], nullptr, xe0, nullptr, 1024, 21, 21, 19, 19, 256, 1, 1, 1, 1, 21, 441, 1, 0, 0));
  run64(mkP(xe0, ewb[1], eb[1], nullptr, f2b, nullptr,  256, 21, 21, 10, 10, 512, 9, 3, 2, 0, 12, 144, 1, 0, 0));
  run64(mkP(f2b, ewb[2], eb[2], nullptr, xe2, nullptr,  512, 12, 12, 10, 10, 128, 1, 1, 1, 1, 12, 144, 1, 0, 0));
  run64(mkP(xe2, ewb[3], eb[3], nullptr, f3b, nullptr,  128, 12, 12,  5,  5, 256, 9, 3, 2, 0,  7,  49, 1, 0, 0));
  run64(mkP(f3b, ewb[4], eb[4], nullptr, xe4, nullptr,  256,  7,  7,  5,  5, 128, 1, 1, 1, 1,  5,  25, 0, 0, 0));
  run64(mkP(xe4, ewb[5], eb[5], nullptr, f4b, nullptr,  128,  5,  5,  3,  3, 256, 9, 3, 1, 0,  5,  25, 1, 0, 0));
  run64(mkP(f4b, ewb[6], eb[6], nullptr, xe6, nullptr,  256,  5,  5,  3,  3, 128, 1, 1, 1, 1,  3,   9, 0, 0, 0));
  run64(mkP(xe6, ewb[7], eb[7], nullptr, f5b, nullptr,  128,  3,  3,  1,  1, 256, 9, 3, 1, 0,  3,   9, 1, 0, 0));

  // all 6 heads in ONE launch (long-K head1 first in group enumeration)
  HeadPack h;
  h.L[0] = mkP(f1b, hwb[1], cb[1], bb[1], nullptr, out, 1024, 21, 21, 19, 19, 6 * 85, 9, 3, 1, 0, 0, 0, 0, 6, 5776);
  h.L[1] = mkP(f0b, hwb[0], cb[0], bb[0], nullptr, out,  512, 40, 40, 38, 38, 4 * 85, 9, 3, 1, 0, 0, 0, 0, 4, 0);
  h.L[2] = mkP(f2b, hwb[2], cb[2], bb[2], nullptr, out,  512, 12, 12, 10, 10, 6 * 85, 9, 3, 1, 0, 0, 0, 0, 6, 7942);
  h.L[3] = mkP(f3b, hwb[3], cb[3], bb[3], nullptr, out,  256,  7,  7,  5,  5, 6 * 85, 9, 3, 1, 0, 0, 0, 0, 6, 8542);
  h.L[4] = mkP(f4b, hwb[4], cb[4], bb[4], nullptr, out,  256,  5,  5,  3,  3, 4 * 85, 9, 3, 1, 0, 0, 0, 0, 4, 8692);
  h.L[5] = mkP(f5b, hwb[5], cb[5], bb[5], nullptr, out,  256,  3,  3,  1,  1, 4 * 85, 9, 3, 1, 0, 0, 0, 0, 4, 8728);

  // host precompute: per-layer, per-XCD slot bases for the balanced group mapping
  int gid = 0;
  for (int x = 0; x < 8; ++x) h.sb[x] = 0;
  for (int li = 0; li < 6; ++li) {
    int nbx = (h.L[li].M + 127) / 128;
    h.nbyA[li] = (h.L[li].Co + 127) / 128;
    h.g0[li] = gid & 7;
    for (int x = 0; x < 8; ++x) {
      int f = ((x - gid) % 8 + 8) % 8;                  // first group offset on XCD x
      int cnt = (f < nbx) ? (nbx - f + 7) / 8 : 0;      // groups of this layer on XCD x
      h.sb[(li + 1) * 8 + x] = h.sb[li * 8 + x] + h.nbyA[li] * cnt;
    }
    gid += nbx;
  }
  int maxSlots = 0;
  for (int x = 0; x < 8; ++x) if (h.sb[48 + x] > maxSlots) maxSlots = h.sb[48 + x];
  head_grouped<<<dim3(8 * maxSlots), 256, 0, stream>>>(h);
}

// Round 9
// 434.922 us; speedup vs baseline: 1.6579x; 1.0127x over previous
//
#include <hip/hip_runtime.h>
#include <hip/hip_bf16.h>

typedef __attribute__((ext_vector_type(8))) short short8;
typedef __attribute__((ext_vector_type(4))) float f32x4;

__device__ __forceinline__ short f2bf(float f) {
  unsigned u = __float_as_uint(f);
  u += 0x7fffu + ((u >> 16) & 1u);   // RNE
  return (short)(u >> 16);
}

__device__ __forceinline__ void gload16(const short* g, short* l) {
  __builtin_amdgcn_global_load_lds(
      (const __attribute__((address_space(1))) unsigned int*)g,
      (__attribute__((address_space(3))) unsigned int*)l, 16, 0, 0);
}

// ---------------- L2 norm scale ------------------------------------------------------
__global__ __launch_bounds__(256) void l2norm_kernel(const float* __restrict__ f0,
                                                     float* __restrict__ scale,
                                                     int C, int P, int total) {
  __shared__ float red[4][64];
  int pl = threadIdx.x & 63;
  int cg = threadIdx.x >> 6;
  int pos = blockIdx.x * 64 + pl;
  float s = 0.f;
  if (pos < total) {
    int n = pos / P, sp = pos - n * P;
    const float* base = f0 + (size_t)n * C * P + sp;
    int c0 = cg * (C >> 2), c1 = c0 + (C >> 2);
    for (int c = c0; c < c1; ++c) {
      float v = base[(size_t)c * P];
      s += v * v;
    }
  }
  red[cg][pl] = s;
  __syncthreads();
  if (threadIdx.x < 64 && pos < total) {
    float tot = red[0][pl] + red[1][pl] + red[2][pl] + red[3][pl];
    scale[pos] = 1.0f / (sqrtf(tot) + 1e-10f);
  }
}

// ------------- NCHW fp32 -> padded NHWC bf16 -----------------------------------------
__global__ __launch_bounds__(256) void to_nhwc_kernel(const float* __restrict__ src,
    short* __restrict__ dst, const float* __restrict__ rowscale,
    const float* __restrict__ chw, int C, int H, int W, int Wp, int nstride, int hh) {
  __shared__ float tile[32][33];
  int n = blockIdx.z;
  int P = H * W;
  int p0 = blockIdx.x * 32, c0 = blockIdx.y * 32;
  int tp = threadIdx.x & 31, tr = threadIdx.x >> 5;
  const float* s = src + (size_t)n * C * P;
  #pragma unroll
  for (int i = 0; i < 4; ++i) {
    int cl = tr + i * 8;
    int p = p0 + tp;
    tile[cl][tp] = (p < P) ? s[(size_t)(c0 + cl) * P + p] : 0.f;
  }
  __syncthreads();
  #pragma unroll
  for (int i = 0; i < 4; ++i) {
    int pl = tr + i * 8;
    int p = p0 + pl;
    if (p >= P) continue;
    int c = c0 + tp;
    float v = tile[tp][pl];
    if (chw)      v *= chw[c];
    if (rowscale) v *= rowscale[n * P + p];
    int y = p / W, x = p - y * W;
    dst[((size_t)n * nstride + (y + hh) * Wp + (x + hh)) * C + c] = f2bf(v);
  }
}

// ---------------- weight repack ------------------------------------------------------
struct WSeg { const float* src; short* dst; int Ci; int S; int elems; };
struct WPrep { WSeg seg[20]; };

__global__ __launch_bounds__(256) void wprep_kernel(WPrep p, int total) {
  int i = blockIdx.x * 256 + threadIdx.x;
  if (i >= total) return;
  int local = i;
  int si = 0;
  while (local >= p.seg[si].elems) { local -= p.seg[si].elems; ++si; }
  WSeg sg = p.seg[si];
  int ci = local % sg.Ci;
  int q  = local / sg.Ci;
  int s  = q % sg.S;
  int co = q / sg.S;
  float v = sg.src[((size_t)co * sg.Ci + ci) * sg.S + s];
  sg.dst[local] = f2bf(v);
}

// ---------------- conv params --------------------------------------------------------
struct ConvP {
  const short* in;   // bf16 padded NHWC [16][iHp][iWp][Ci]
  const short* w;    // bf16 [Co][S][Ci]
  const float* b1;   // bias (extra) / cls bias (head)
  const float* b2;   // box bias (head)
  short* out_bf;     // extra: padded bf16 NHWC out
  float* out_f;      // head: packed d_out
  int M, Ci, iHp, iWp, Ho, Wo, Co;
  int S, kdim, stride, ioff;
  int oWp, onstride, oh;
  int mbox, row_base;
};

// --- BK-parameterized 2-buffer, 1-barrier/K-step implicit-GEMM core + swizzle --------
// Per K-step: stage(k+1) into buf^1 -> ds_read buf -> BK/32 x AM x AN MFMA ->
// __syncthreads (vmcnt0 drain = RAW for k+1, WAR for buf). Heads: BK=64 (LDS 64KB,
// 2 blocks/CU). Extras: BK=128 (fewer serialized steps; grids < CU count so the
// 64KB LDS occupancy cap is irrelevant). Hand-vmcnt variants regress here (r4/r5).
// Swizzle (rule #21 both-sides): stage global chunk (t&(CPR-1))^(sr&(CPR-1)) to linear
// LDS; read chunk ((kk<<2)|kgrp)^(r&(CPR-1)) — same involution, bank-uniform b128.
template<int BM, int BN, int BK, bool HEAD>
__device__ __forceinline__ void conv_core(const ConvP p, int bx, int by) {
  constexpr int CPR = BK / 8;                      // 16B chunks per row
  constexpr int RP  = 2048 / BK;                   // rows staged per pass
  constexpr int NRA = BM / RP, NRB = BN / RP;
  constexpr int AM = BM / 32, AN = BN / 32, KK = BK / 32;
  constexpr int ABUF = BM * BK, BBUF = BN * BK;    // shorts per buffer
  __shared__ short As[2 * ABUF];
  __shared__ short Bs[2 * BBUF];
  const int t = threadIdx.x, lane = t & 63, wave = t >> 6;
  const int HW = p.Ho * p.Wo;
  const int sr = t / CPR;                          // row-in-pass 0..RP-1
  const int slot = ((t & (CPR - 1)) ^ (sr & (CPR - 1))) * 8;  // pre-swizzled k-slot

  const short* aBase[NRA];
  const short* bBase[NRB];
  #pragma unroll
  for (int i = 0; i < NRA; ++i) {
    int pos = bx * BM + sr + i * RP; if (pos >= p.M) pos = p.M - 1;
    int n = pos / HW, rem = pos - n * HW;
    int yo = rem / p.Wo, xo = rem - yo * p.Wo;
    aBase[i] = p.in + ((size_t)(n * p.iHp + yo * p.stride + p.ioff) * p.iWp
                      + xo * p.stride + p.ioff) * p.Ci + slot;
  }
  #pragma unroll
  for (int i = 0; i < NRB; ++i) {
    int co = by * BN + sr + i * RP; if (co >= p.Co) co = p.Co - 1;
    bBase[i] = p.w + (size_t)co * p.S * p.Ci + slot;
  }
  const int cs = p.Ci / BK;          // BK-ci chunks per tap (>=1, power of 2)
  const int total = p.S * cs;

  auto stage = [&](int buf, int aoff, int boff) {
    #pragma unroll
    for (int i = 0; i < NRA; ++i)
      gload16(aBase[i] + aoff, &As[buf * ABUF + i * 2048 + t * 8]);
    #pragma unroll
    for (int i = 0; i < NRB; ++i)
      gload16(bBase[i] + boff, &Bs[buf * BBUF + i * 2048 + t * 8]);
  };

  int ntap = 0, ncc = 0;
  auto aoff_cur = [&]() -> int {
    if (p.S == 1) return ncc * BK;
    unsigned dy = (unsigned)ntap / 3u;
    int dx = ntap - (int)dy * 3;
    return ((int)dy * p.iWp + dx) * p.Ci + ncc * BK;
  };

  stage(0, aoff_cur(), 0);
  ++ncc; if (ncc == cs) { ncc = 0; ++ntap; }
  __syncthreads();                       // tile 0 landed

  f32x4 acc[AM][AN];
  #pragma unroll
  for (int i = 0; i < AM; ++i)
    #pragma unroll
    for (int j = 0; j < AN; ++j)
      acc[i][j] = (f32x4){0.f, 0.f, 0.f, 0.f};

  const int wr = (wave >> 1) * (BM / 2), wc = (wave & 1) * (BN / 2);
  const int lrow = lane & 15, kgrp = lane >> 4;

  int cur = 0;
  for (int ks = 0; ks < total; ++ks) {
    if (ks + 1 < total) {                // issue next tile's loads FIRST (overlap)
      stage(cur ^ 1, aoff_cur(), (ks + 1) * BK);
      ++ncc; if (ncc == cs) { ncc = 0; ++ntap; }
    }
    const short* aRd0 = &As[cur * ABUF];
    const short* bRd0 = &Bs[cur * BBUF];
    short8 a[AM][KK], b[AN][KK];
    #pragma unroll
    for (int i = 0; i < AM; ++i) {
      int r = wr + i * 16 + lrow;
      #pragma unroll
      for (int kk = 0; kk < KK; ++kk) {
        int ch = ((kk << 2) | kgrp) ^ (r & (CPR - 1));
        a[i][kk] = *reinterpret_cast<const short8*>(aRd0 + r * BK + ch * 8);
      }
    }
    #pragma unroll
    for (int j = 0; j < AN; ++j) {
      int r = wc + j * 16 + lrow;
      #pragma unroll
      for (int kk = 0; kk < KK; ++kk) {
        int ch = ((kk << 2) | kgrp) ^ (r & (CPR - 1));
        b[j][kk] = *reinterpret_cast<const short8*>(bRd0 + r * BK + ch * 8);
      }
    }
    #pragma unroll
    for (int kk = 0; kk < KK; ++kk)
      #pragma unroll
      for (int i = 0; i < AM; ++i)
        #pragma unroll
        for (int j = 0; j < AN; ++j)
          acc[i][j] = __builtin_amdgcn_mfma_f32_16x16x32_bf16(a[i][kk], b[j][kk], acc[i][j], 0, 0, 0);
    __syncthreads();                     // drains vmcnt(0): next tile ready; reads done
    cur ^= 1;
  }

  const int mk = p.mbox * 81;
  const int rb_ = (lane >> 4) * 4, cl_ = lane & 15;
  #pragma unroll
  for (int i = 0; i < AM; ++i)
    #pragma unroll
    for (int j = 0; j < AN; ++j)
      #pragma unroll
      for (int q = 0; q < 4; ++q) {
        int po = bx * BM + wr + i * 16 + rb_ + q;
        int co = by * BN + wc + j * 16 + cl_;
        if (po >= p.M || co >= p.Co) continue;
        float v = acc[i][j][q];
        if (!HEAD) {
          int n2 = po / HW, sp = po - n2 * HW;
          int y = sp / p.Wo, x = sp - y * p.Wo;
          float v2 = fmaxf(v + p.b1[co], 0.f);
          p.out_bf[((size_t)n2 * p.onstride + (y + p.oh) * p.oWp + (x + p.oh)) * p.Co + co] = f2bf(v2);
        } else {
          int n2 = po / HW, sp = po - n2 * HW;
          int mi, col; float bias;
          if (co < mk) { mi = co / 81; col = co - mi * 81; bias = p.b1[co]; }
          else { int cbx = co - mk; mi = cbx >> 2; col = 81 + (cbx & 3); bias = p.b2[cbx]; }
          size_t orow = (size_t)n2 * 8732 + p.row_base + (size_t)sp * p.mbox + mi;
          p.out_f[orow * 85 + col] = v + bias;
        }
      }
}

__global__ __launch_bounds__(256) void conv_tile64(ConvP p) {
  conv_core<64, 64, 128, false>(p, blockIdx.x, blockIdx.y);
}

// ------ grouped head kernel: group-preserving, round-robin-balanced XCD mapping ------
// Reuse unit = group (layer, bx) with nby member blocks sharing one A-panel. Hardware
// maps physical block p -> XCD p&7. Groups assigned round-robin (gid%8 -> XCD) so each
// XCD gets a proportional mix of long-K and short-K groups; a group's members occupy
// consecutive slots of ONE XCD. sb[li*8+x] = first slot of layer li on XCD x.
struct HeadPack { ConvP L[6]; int g0[6]; int nbyA[6]; int sb[56]; };

__global__ __launch_bounds__(256) void head_grouped(HeadPack h) {
  int p = blockIdx.x, x = p & 7, s = p >> 3;
  if (s >= h.sb[48 + x]) return;         // padding block
  int li = 0;
  #pragma unroll
  for (int i = 1; i < 6; ++i) if (s >= h.sb[i * 8 + x]) li = i;
  int r = s - h.sb[li * 8 + x];
  int nby = h.nbyA[li];
  int k = r / nby, by = r - k * nby;
  int bx = ((x - h.g0[li]) & 7) + 8 * k; // bx of the k-th group of layer li on XCD x
  conv_core<128, 128, 64, true>(h.L[li], bx, by);
}

extern "C" void kernel_launch(void* const* d_in, const int* in_sizes, int n_in,
                              void* d_out, int out_size, void* d_ws, size_t ws_size,
                              hipStream_t stream) {
  const float* feat0 = (const float*)d_in[0];
  const float* feat1 = (const float*)d_in[1];
  const float* l2w   = (const float*)d_in[2];
  const float* ew[8]; const float* eb[8];
  for (int i = 0; i < 8; ++i) { ew[i] = (const float*)d_in[3 + 2 * i]; eb[i] = (const float*)d_in[4 + 2 * i]; }
  const float* cw[6]; const float* cb[6]; const float* bw[6]; const float* bb[6];
  for (int i = 0; i < 6; ++i) {
    cw[i] = (const float*)d_in[19 + 4 * i]; cb[i] = (const float*)d_in[20 + 4 * i];
    bw[i] = (const float*)d_in[21 + 4 * i]; bb[i] = (const float*)d_in[22 + 4 * i];
  }
  float* out = (float*)d_out;
  char* ws = (char*)d_ws;
  size_t off = 0;
  auto alloc = [&](size_t bytes) -> char* {
    char* p = ws + off;
    off = (off + bytes + 255) & ~(size_t)255;
    return p;
  };
  float* scale0 = (float*)alloc(23104 * 4);
  char* featStart = ws + off;
  short* f0b = (short*)alloc((size_t)16 * 40 * 40 * 512 * 2);   // 38x38, h=1
  short* f1b = (short*)alloc((size_t)16 * 21 * 21 * 1024 * 2);  // 19x19, h=1
  short* xe0 = (short*)alloc((size_t)16 * 21 * 21 * 256 * 2);   // 19x19, h=1
  short* f2b = (short*)alloc((size_t)16 * 12 * 12 * 512 * 2);   // 10x10, h=1
  short* xe2 = (short*)alloc((size_t)16 * 12 * 12 * 128 * 2);   // 10x10, h=1
  short* f3b = (short*)alloc((size_t)16 * 7 * 7 * 256 * 2);     // 5x5,  h=1
  short* xe4 = (short*)alloc((size_t)16 * 5 * 5 * 128 * 2);     // 5x5,  h=0
  short* f4b = (short*)alloc((size_t)16 * 5 * 5 * 256 * 2);     // 3x3,  h=1
  short* xe6 = (short*)alloc((size_t)16 * 3 * 3 * 128 * 2);     // 3x3,  h=0
  short* f5b = (short*)alloc((size_t)16 * 3 * 3 * 256 * 2);     // 1x1,  h=1
  size_t featBytes = (size_t)((ws + off) - featStart);

  static const int eCo[8] = {256, 512, 128, 256, 128, 256, 128, 256};
  static const int eCi[8] = {1024, 256, 512, 128, 256, 128, 256, 128};
  static const int eS[8]  = {1, 9, 1, 9, 1, 9, 1, 9};
  static const int mbox[6] = {4, 6, 6, 6, 4, 4};
  static const int hCi[6] = {512, 1024, 512, 256, 256, 256};

  WPrep wp; int total = 0; int segi = 0;
  short* ewb[8]; short* hwb[6];
  for (int i = 0; i < 8; ++i) {
    int e = eCo[i] * eCi[i] * eS[i];
    ewb[i] = (short*)alloc((size_t)e * 2);
    wp.seg[segi++] = {ew[i], ewb[i], eCi[i], eS[i], e};
    total += e;
  }
  for (int L = 0; L < 6; ++L) {
    int co = mbox[L] * 85;
    int e = co * hCi[L] * 9;
    hwb[L] = (short*)alloc((size_t)e * 2);
    int ecls = mbox[L] * 81 * hCi[L] * 9;
    wp.seg[segi++] = {cw[L], hwb[L], hCi[L], 9, ecls};
    wp.seg[segi++] = {bw[L], hwb[L] + (size_t)mbox[L] * 81 * 9 * hCi[L], hCi[L], 9, e - ecls};
    total += e;
  }

  hipMemsetAsync(featStart, 0, featBytes, stream);
  l2norm_kernel<<<dim3((23104 + 63) / 64), 256, 0, stream>>>(feat0, scale0, 512, 1444, 23104);
  to_nhwc_kernel<<<dim3(46, 16, 16), 256, 0, stream>>>(feat0, f0b, scale0, l2w, 512, 38, 38, 40, 1600, 1);
  to_nhwc_kernel<<<dim3(12, 32, 16), 256, 0, stream>>>(feat1, f1b, nullptr, nullptr, 1024, 19, 19, 21, 441, 1);
  wprep_kernel<<<dim3((total + 255) / 256), 256, 0, stream>>>(wp, total);

  auto mkP = [&](const short* in, const short* wbuf, const float* b1, const float* b2,
                 short* outb, float* outf, int Ci, int iHp, int iWp, int Ho, int Wo,
                 int Co, int S, int kd, int st, int ioff, int oWp, int onstride, int oh,
                 int m, int rb) {
    ConvP p{}; p.in = in; p.w = wbuf; p.b1 = b1; p.b2 = b2; p.out_bf = outb; p.out_f = outf;
    p.M = 16 * Ho * Wo; p.Ci = Ci; p.iHp = iHp; p.iWp = iWp; p.Ho = Ho; p.Wo = Wo; p.Co = Co;
    p.S = S; p.kdim = kd; p.stride = st; p.ioff = ioff;
    p.oWp = oWp; p.onstride = onstride; p.oh = oh; p.mbox = m; p.row_base = rb;
    return p;
  };
  auto run64 = [&](ConvP p) {
    conv_tile64<<<dim3((p.M + 63) / 64, (p.Co + 63) / 64), 256, 0, stream>>>(p);
  };

  // extras chain (BK=128 pipelined 64x64, 64KB LDS; grids < CU count so occupancy
  // cap is irrelevant — step count is the cost, halved vs BK=64)
  run64(mkP(f1b, ewb[0], eb[0], nullptr, xe0, nullptr, 1024, 21, 21, 19, 19, 256, 1, 1, 1, 1, 21, 441, 1, 0, 0));
  run64(mkP(xe0, ewb[1], eb[1], nullptr, f2b, nullptr,  256, 21, 21, 10, 10, 512, 9, 3, 2, 0, 12, 144, 1, 0, 0));
  run64(mkP(f2b, ewb[2], eb[2], nullptr, xe2, nullptr,  512, 12, 12, 10, 10, 128, 1, 1, 1, 1, 12, 144, 1, 0, 0));
  run64(mkP(xe2, ewb[3], eb[3], nullptr, f3b, nullptr,  128, 12, 12,  5,  5, 256, 9, 3, 2, 0,  7,  49, 1, 0, 0));
  run64(mkP(f3b, ewb[4], eb[4], nullptr, xe4, nullptr,  256,  7,  7,  5,  5, 128, 1, 1, 1, 1,  5,  25, 0, 0, 0));
  run64(mkP(xe4, ewb[5], eb[5], nullptr, f4b, nullptr,  128,  5,  5,  3,  3, 256, 9, 3, 1, 0,  5,  25, 1, 0, 0));
  run64(mkP(f4b, ewb[6], eb[6], nullptr, xe6, nullptr,  256,  5,  5,  3,  3, 128, 1, 1, 1, 1,  3,   9, 0, 0, 0));
  run64(mkP(xe6, ewb[7], eb[7], nullptr, f5b, nullptr,  128,  3,  3,  1,  1, 256, 9, 3, 1, 0,  3,   9, 1, 0, 0));

  // all 6 heads in ONE launch (long-K head1 first in group enumeration)
  HeadPack h;
  h.L[0] = mkP(f1b, hwb[1], cb[1], bb[1], nullptr, out, 1024, 21, 21, 19, 19, 6 * 85, 9, 3, 1, 0, 0, 0, 0, 6, 5776);
  h.L[1] = mkP(f0b, hwb[0], cb[0], bb[0], nullptr, out,  512, 40, 40, 38, 38, 4 * 85, 9, 3, 1, 0, 0, 0, 0, 4, 0);
  h.L[2] = mkP(f2b, hwb[2], cb[2], bb[2], nullptr, out,  512, 12, 12, 10, 10, 6 * 85, 9, 3, 1, 0, 0, 0, 0, 6, 7942);
  h.L[3] = mkP(f3b, hwb[3], cb[3], bb[3], nullptr, out,  256,  7,  7,  5,  5, 6 * 85, 9, 3, 1, 0, 0, 0, 0, 6, 8542);
  h.L[4] = mkP(f4b, hwb[4], cb[4], bb[4], nullptr, out,  256,  5,  5,  3,  3, 4 * 85, 9, 3, 1, 0, 0, 0, 0, 4, 8692);
  h.L[5] = mkP(f5b, hwb[5], cb[5], bb[5], nullptr, out,  256,  3,  3,  1,  1, 4 * 85, 9, 3, 1, 0, 0, 0, 0, 4, 8728);

  // host precompute: per-layer, per-XCD slot bases for the balanced group mapping
  int gid = 0;
  for (int x = 0; x < 8; ++x) h.sb[x] = 0;
  for (int li = 0; li < 6; ++li) {
    int nbx = (h.L[li].M + 127) / 128;
    h.nbyA[li] = (h.L[li].Co + 127) / 128;
    h.g0[li] = gid & 7;
    for (int x = 0; x < 8; ++x) {
      int f = ((x - gid) % 8 + 8) % 8;                  // first group offset on XCD x
      int cnt = (f < nbx) ? (nbx - f + 7) / 8 : 0;      // groups of this layer on XCD x
      h.sb[(li + 1) * 8 + x] = h.sb[li * 8 + x] + h.nbyA[li] * cnt;
    }
    gid += nbx;
  }
  int maxSlots = 0;
  for (int x = 0; x < 8; ++x) if (h.sb[48 + x] > maxSlots) maxSlots = h.sb[48 + x];
  head_grouped<<<dim3(8 * maxSlots), 256, 0, stream>>>(h);
}

// Round 10
// 383.265 us; speedup vs baseline: 1.8814x; 1.1348x over previous
//
#include <hip/hip_runtime.h>
#include <hip/hip_bf16.h>

typedef __attribute__((ext_vector_type(8))) short short8;
typedef __attribute__((ext_vector_type(4))) float f32x4;

__device__ __forceinline__ short f2bf(float f) {
  unsigned u = __float_as_uint(f);
  u += 0x7fffu + ((u >> 16) & 1u);   // RNE
  return (short)(u >> 16);
}

__device__ __forceinline__ void gload16(const short* g, short* l) {
  __builtin_amdgcn_global_load_lds(
      (const __attribute__((address_space(1))) unsigned int*)g,
      (__attribute__((address_space(3))) unsigned int*)l, 16, 0, 0);
}

// ------ fused L2Norm + NCHW fp32 -> padded NHWC bf16 for feat0 -----------------------
// Block = 32 positions x all 512 channels. Pass 1: per-position sum of squares
// (coalesced NCHW reads). Pass 2: re-read (L2-hot) through 32x33 transpose tile,
// scale by l2w[c]/||x||, write bf16 NHWC. One 94.5MB HBM read instead of two.
__global__ __launch_bounds__(256) void f0prep_kernel(const float* __restrict__ src,
    short* __restrict__ dst, const float* __restrict__ l2w,
    int H, int W, int Wp, int nstride, int hh) {
  constexpr int C = 512;
  __shared__ float red[8][32];
  __shared__ float sscale[32];
  __shared__ float tile[32][33];
  int n = blockIdx.z;
  int P = H * W;
  int p0 = blockIdx.x * 32;
  int pl = threadIdx.x & 31, cg = threadIdx.x >> 5;
  const float* s = src + (size_t)n * C * P;
  float ss = 0.f;
  int p = p0 + pl;
  if (p < P) {
    for (int k = 0; k < 64; ++k) {
      float v = s[(size_t)(cg * 64 + k) * P + p];
      ss += v * v;
    }
  }
  red[cg][pl] = ss;
  __syncthreads();
  if (threadIdx.x < 32) {
    float tot = 0.f;
    #pragma unroll
    for (int g = 0; g < 8; ++g) tot += red[g][threadIdx.x];
    sscale[threadIdx.x] = 1.0f / (sqrtf(tot) + 1e-10f);
  }
  __syncthreads();
  for (int ct = 0; ct < 16; ++ct) {
    int c0 = ct * 32;
    __syncthreads();
    #pragma unroll
    for (int i = 0; i < 4; ++i) {
      int cl = cg + i * 8;
      tile[cl][pl] = (p < P) ? s[(size_t)(c0 + cl) * P + p] : 0.f;
    }
    __syncthreads();
    #pragma unroll
    for (int i = 0; i < 4; ++i) {
      int pll = cg + i * 8;
      int pp = p0 + pll;
      if (pp >= P) continue;
      int c = c0 + pl;
      float v = tile[pl][pll] * l2w[c] * sscale[pll];
      int y = pp / W, x = pp - y * W;
      dst[((size_t)n * nstride + (y + hh) * Wp + (x + hh)) * C + c] = f2bf(v);
    }
  }
}

// ------------- NCHW fp32 -> padded NHWC bf16 (feat1) ---------------------------------
__global__ __launch_bounds__(256) void to_nhwc_kernel(const float* __restrict__ src,
    short* __restrict__ dst, int C, int H, int W, int Wp, int nstride, int hh) {
  __shared__ float tile[32][33];
  int n = blockIdx.z;
  int P = H * W;
  int p0 = blockIdx.x * 32, c0 = blockIdx.y * 32;
  int tp = threadIdx.x & 31, tr = threadIdx.x >> 5;
  const float* s = src + (size_t)n * C * P;
  #pragma unroll
  for (int i = 0; i < 4; ++i) {
    int cl = tr + i * 8;
    int p = p0 + tp;
    tile[cl][tp] = (p < P) ? s[(size_t)(c0 + cl) * P + p] : 0.f;
  }
  __syncthreads();
  #pragma unroll
  for (int i = 0; i < 4; ++i) {
    int pl = tr + i * 8;
    int p = p0 + pl;
    if (p >= P) continue;
    int c = c0 + tp;
    float v = tile[tp][pl];
    int y = p / W, x = p - y * W;
    dst[((size_t)n * nstride + (y + hh) * Wp + (x + hh)) * C + c] = f2bf(v);
  }
}

// ---------------- weight repack ------------------------------------------------------
struct WSeg { const float* src; short* dst; int Ci; int S; int elems; };
struct WPrep { WSeg seg[20]; };

__global__ __launch_bounds__(256) void wprep_kernel(WPrep p, int total) {
  int i = blockIdx.x * 256 + threadIdx.x;
  if (i >= total) return;
  int local = i;
  int si = 0;
  while (local >= p.seg[si].elems) { local -= p.seg[si].elems; ++si; }
  WSeg sg = p.seg[si];
  int ci = local % sg.Ci;
  int q  = local / sg.Ci;
  int s  = q % sg.S;
  int co = q / sg.S;
  float v = sg.src[((size_t)co * sg.Ci + ci) * sg.S + s];
  sg.dst[local] = f2bf(v);
}

// ---------------- conv params --------------------------------------------------------
struct ConvP {
  const short* in;   // bf16 padded NHWC [16][iHp][iWp][Ci]
  const short* w;    // bf16 [Co][S][Ci]
  const float* b1;   // bias (extra) / cls bias (head)
  const float* b2;   // box bias (head)
  short* out_bf;     // extra: padded bf16 NHWC out
  float* out_f;      // head: packed d_out
  int M, Ci, iHp, iWp, Ho, Wo, Co;
  int S, kdim, stride, ioff;
  int oWp, onstride, oh;
  int mbox, row_base;
};

// --- BK/wave-parameterized 2-buffer, 1-barrier/K-step implicit-GEMM core + swizzle ---
// Per K-step: stage(k+1) into buf^1 -> ds_read buf -> KK x AM x AN MFMA ->
// __syncthreads (vmcnt0 drain = RAW for k+1, WAR for buf). Heads: 8 waves (2Mx4N,
// 512 thr), 128x128/BK=64, 64KB LDS -> 2 blocks/CU = 16 waves/CU (TLP for latency
// hiding). Extras: 4 waves, 64x64/BK=128. Hand-vmcnt variants regress here (r4/r5).
// Swizzle (rule #21 both-sides): stage global chunk (t&(CPR-1))^(sr&(CPR-1)) to linear
// LDS; read chunk ((kk<<2)|kgrp)^(r&(CPR-1)) — same involution, bank-uniform b128.
template<int BM, int BN, int BK, int WM, int WN, bool HEAD>
__device__ __forceinline__ void conv_core(const ConvP p, int bx, int by) {
  constexpr int NT  = WM * WN * 64;                // threads
  constexpr int CPR = BK / 8;                      // 16B chunks per row
  constexpr int RPP = NT / CPR;                    // rows staged per pass
  constexpr int NRA = BM / RPP, NRB = BN / RPP;
  constexpr int AM = BM / WM / 16, AN = BN / WN / 16, KK = BK / 32;
  constexpr int ABUF = BM * BK, BBUF = BN * BK;    // shorts per buffer
  __shared__ short As[2 * ABUF];
  __shared__ short Bs[2 * BBUF];
  const int t = threadIdx.x, lane = t & 63, wave = t >> 6;
  const int HW = p.Ho * p.Wo;
  const int sr = t / CPR;                          // row-in-pass 0..RPP-1
  const int slot = ((t & (CPR - 1)) ^ (sr & (CPR - 1))) * 8;  // pre-swizzled k-slot

  const short* aBase[NRA];
  const short* bBase[NRB];
  #pragma unroll
  for (int i = 0; i < NRA; ++i) {
    int pos = bx * BM + sr + i * RPP; if (pos >= p.M) pos = p.M - 1;
    int n = pos / HW, rem = pos - n * HW;
    int yo = rem / p.Wo, xo = rem - yo * p.Wo;
    aBase[i] = p.in + ((size_t)(n * p.iHp + yo * p.stride + p.ioff) * p.iWp
                      + xo * p.stride + p.ioff) * p.Ci + slot;
  }
  #pragma unroll
  for (int i = 0; i < NRB; ++i) {
    int co = by * BN + sr + i * RPP; if (co >= p.Co) co = p.Co - 1;
    bBase[i] = p.w + (size_t)co * p.S * p.Ci + slot;
  }
  const int cs = p.Ci / BK;          // BK-ci chunks per tap (>=1, power of 2)
  const int total = p.S * cs;

  auto stage = [&](int buf, int aoff, int boff) {
    #pragma unroll
    for (int i = 0; i < NRA; ++i)
      gload16(aBase[i] + aoff, &As[buf * ABUF + i * (NT * 8) + t * 8]);
    #pragma unroll
    for (int i = 0; i < NRB; ++i)
      gload16(bBase[i] + boff, &Bs[buf * BBUF + i * (NT * 8) + t * 8]);
  };

  int ntap = 0, ncc = 0;
  auto aoff_cur = [&]() -> int {
    if (p.S == 1) return ncc * BK;
    unsigned dy = (unsigned)ntap / 3u;
    int dx = ntap - (int)dy * 3;
    return ((int)dy * p.iWp + dx) * p.Ci + ncc * BK;
  };

  stage(0, aoff_cur(), 0);
  ++ncc; if (ncc == cs) { ncc = 0; ++ntap; }
  __syncthreads();                       // tile 0 landed

  f32x4 acc[AM][AN];
  #pragma unroll
  for (int i = 0; i < AM; ++i)
    #pragma unroll
    for (int j = 0; j < AN; ++j)
      acc[i][j] = (f32x4){0.f, 0.f, 0.f, 0.f};

  const int wr = (wave / WN) * (BM / WM), wc = (wave % WN) * (BN / WN);
  const int lrow = lane & 15, kgrp = lane >> 4;

  int cur = 0;
  for (int ks = 0; ks < total; ++ks) {
    if (ks + 1 < total) {                // issue next tile's loads FIRST (overlap)
      stage(cur ^ 1, aoff_cur(), (ks + 1) * BK);
      ++ncc; if (ncc == cs) { ncc = 0; ++ntap; }
    }
    const short* aRd0 = &As[cur * ABUF];
    const short* bRd0 = &Bs[cur * BBUF];
    short8 a[AM][KK], b[AN][KK];
    #pragma unroll
    for (int i = 0; i < AM; ++i) {
      int r = wr + i * 16 + lrow;
      #pragma unroll
      for (int kk = 0; kk < KK; ++kk) {
        int ch = ((kk << 2) | kgrp) ^ (r & (CPR - 1));
        a[i][kk] = *reinterpret_cast<const short8*>(aRd0 + r * BK + ch * 8);
      }
    }
    #pragma unroll
    for (int j = 0; j < AN; ++j) {
      int r = wc + j * 16 + lrow;
      #pragma unroll
      for (int kk = 0; kk < KK; ++kk) {
        int ch = ((kk << 2) | kgrp) ^ (r & (CPR - 1));
        b[j][kk] = *reinterpret_cast<const short8*>(bRd0 + r * BK + ch * 8);
      }
    }
    #pragma unroll
    for (int kk = 0; kk < KK; ++kk)
      #pragma unroll
      for (int i = 0; i < AM; ++i)
        #pragma unroll
        for (int j = 0; j < AN; ++j)
          acc[i][j] = __builtin_amdgcn_mfma_f32_16x16x32_bf16(a[i][kk], b[j][kk], acc[i][j], 0, 0, 0);
    __syncthreads();                     // drains vmcnt(0): next tile ready; reads done
    cur ^= 1;
  }

  const int mk = p.mbox * 81;
  const int rb_ = (lane >> 4) * 4, cl_ = lane & 15;
  #pragma unroll
  for (int i = 0; i < AM; ++i)
    #pragma unroll
    for (int j = 0; j < AN; ++j)
      #pragma unroll
      for (int q = 0; q < 4; ++q) {
        int po = bx * BM + wr + i * 16 + rb_ + q;
        int co = by * BN + wc + j * 16 + cl_;
        if (po >= p.M || co >= p.Co) continue;
        float v = acc[i][j][q];
        if (!HEAD) {
          int n2 = po / HW, sp = po - n2 * HW;
          int y = sp / p.Wo, x = sp - y * p.Wo;
          float v2 = fmaxf(v + p.b1[co], 0.f);
          p.out_bf[((size_t)n2 * p.onstride + (y + p.oh) * p.oWp + (x + p.oh)) * p.Co + co] = f2bf(v2);
        } else {
          int n2 = po / HW, sp = po - n2 * HW;
          int mi, col; float bias;
          if (co < mk) { mi = co / 81; col = co - mi * 81; bias = p.b1[co]; }
          else { int cbx = co - mk; mi = cbx >> 2; col = 81 + (cbx & 3); bias = p.b2[cbx]; }
          size_t orow = (size_t)n2 * 8732 + p.row_base + (size_t)sp * p.mbox + mi;
          p.out_f[orow * 85 + col] = v + bias;
        }
      }
}

__global__ __launch_bounds__(256) void conv_tile64(ConvP p) {
  conv_core<64, 64, 128, 2, 2, false>(p, blockIdx.x, blockIdx.y);
}

// ------ grouped head kernel: group-preserving, round-robin-balanced XCD mapping ------
// Reuse unit = group (layer, bx) with nby member blocks sharing one A-panel. Hardware
// maps physical block p -> XCD p&7. Groups assigned round-robin (gid%8 -> XCD) so each
// XCD gets a proportional mix of long-K and short-K groups; a group's members occupy
// consecutive slots of ONE XCD. sb[li*8+x] = first slot of layer li on XCD x.
struct HeadPack { ConvP L[6]; int g0[6]; int nbyA[6]; int sb[56]; };

__global__ __launch_bounds__(512) void head_grouped(HeadPack h) {
  int p = blockIdx.x, x = p & 7, s = p >> 3;
  if (s >= h.sb[48 + x]) return;         // padding block
  int li = 0;
  #pragma unroll
  for (int i = 1; i < 6; ++i) if (s >= h.sb[i * 8 + x]) li = i;
  int r = s - h.sb[li * 8 + x];
  int nby = h.nbyA[li];
  int k = r / nby, by = r - k * nby;
  int bx = ((x - h.g0[li]) & 7) + 8 * k; // bx of the k-th group of layer li on XCD x
  conv_core<128, 128, 64, 2, 4, true>(h.L[li], bx, by);
}

extern "C" void kernel_launch(void* const* d_in, const int* in_sizes, int n_in,
                              void* d_out, int out_size, void* d_ws, size_t ws_size,
                              hipStream_t stream) {
  const float* feat0 = (const float*)d_in[0];
  const float* feat1 = (const float*)d_in[1];
  const float* l2w   = (const float*)d_in[2];
  const float* ew[8]; const float* eb[8];
  for (int i = 0; i < 8; ++i) { ew[i] = (const float*)d_in[3 + 2 * i]; eb[i] = (const float*)d_in[4 + 2 * i]; }
  const float* cw[6]; const float* cb[6]; const float* bw[6]; const float* bb[6];
  for (int i = 0; i < 6; ++i) {
    cw[i] = (const float*)d_in[19 + 4 * i]; cb[i] = (const float*)d_in[20 + 4 * i];
    bw[i] = (const float*)d_in[21 + 4 * i]; bb[i] = (const float*)d_in[22 + 4 * i];
  }
  float* out = (float*)d_out;
  char* ws = (char*)d_ws;
  size_t off = 0;
  auto alloc = [&](size_t bytes) -> char* {
    char* p = ws + off;
    off = (off + bytes + 255) & ~(size_t)255;
    return p;
  };
  char* featStart = ws + off;
  short* f0b = (short*)alloc((size_t)16 * 40 * 40 * 512 * 2);   // 38x38, h=1
  short* f1b = (short*)alloc((size_t)16 * 21 * 21 * 1024 * 2);  // 19x19, h=1
  short* xe0 = (short*)alloc((size_t)16 * 21 * 21 * 256 * 2);   // 19x19, h=1
  short* f2b = (short*)alloc((size_t)16 * 12 * 12 * 512 * 2);   // 10x10, h=1
  short* xe2 = (short*)alloc((size_t)16 * 12 * 12 * 128 * 2);   // 10x10, h=1
  short* f3b = (short*)alloc((size_t)16 * 7 * 7 * 256 * 2);     // 5x5,  h=1
  short* xe4 = (short*)alloc((size_t)16 * 5 * 5 * 128 * 2);     // 5x5,  h=0
  short* f4b = (short*)alloc((size_t)16 * 5 * 5 * 256 * 2);     // 3x3,  h=1
  short* xe6 = (short*)alloc((size_t)16 * 3 * 3 * 128 * 2);     // 3x3,  h=0
  short* f5b = (short*)alloc((size_t)16 * 3 * 3 * 256 * 2);     // 1x1,  h=1
  size_t featBytes = (size_t)((ws + off) - featStart);

  static const int eCo[8] = {256, 512, 128, 256, 128, 256, 128, 256};
  static const int eCi[8] = {1024, 256, 512, 128, 256, 128, 256, 128};
  static const int eS[8]  = {1, 9, 1, 9, 1, 9, 1, 9};
  static const int mbox[6] = {4, 6, 6, 6, 4, 4};
  static const int hCi[6] = {512, 1024, 512, 256, 256, 256};

  WPrep wp; int total = 0; int segi = 0;
  short* ewb[8]; short* hwb[6];
  for (int i = 0; i < 8; ++i) {
    int e = eCo[i] * eCi[i] * eS[i];
    ewb[i] = (short*)alloc((size_t)e * 2);
    wp.seg[segi++] = {ew[i], ewb[i], eCi[i], eS[i], e};
    total += e;
  }
  for (int L = 0; L < 6; ++L) {
    int co = mbox[L] * 85;
    int e = co * hCi[L] * 9;
    hwb[L] = (short*)alloc((size_t)e * 2);
    int ecls = mbox[L] * 81 * hCi[L] * 9;
    wp.seg[segi++] = {cw[L], hwb[L], hCi[L], 9, ecls};
    wp.seg[segi++] = {bw[L], hwb[L] + (size_t)mbox[L] * 81 * 9 * hCi[L], hCi[L], 9, e - ecls};
    total += e;
  }

  hipMemsetAsync(featStart, 0, featBytes, stream);
  f0prep_kernel<<<dim3(46, 1, 16), 256, 0, stream>>>(feat0, f0b, l2w, 38, 38, 40, 1600, 1);
  to_nhwc_kernel<<<dim3(12, 32, 16), 256, 0, stream>>>(feat1, f1b, 1024, 19, 19, 21, 441, 1);
  wprep_kernel<<<dim3((total + 255) / 256), 256, 0, stream>>>(wp, total);

  auto mkP = [&](const short* in, const short* wbuf, const float* b1, const float* b2,
                 short* outb, float* outf, int Ci, int iHp, int iWp, int Ho, int Wo,
                 int Co, int S, int kd, int st, int ioff, int oWp, int onstride, int oh,
                 int m, int rb) {
    ConvP p{}; p.in = in; p.w = wbuf; p.b1 = b1; p.b2 = b2; p.out_bf = outb; p.out_f = outf;
    p.M = 16 * Ho * Wo; p.Ci = Ci; p.iHp = iHp; p.iWp = iWp; p.Ho = Ho; p.Wo = Wo; p.Co = Co;
    p.S = S; p.kdim = kd; p.stride = st; p.ioff = ioff;
    p.oWp = oWp; p.onstride = onstride; p.oh = oh; p.mbox = m; p.row_base = rb;
    return p;
  };
  auto run64 = [&](ConvP p) {
    conv_tile64<<<dim3((p.M + 63) / 64, (p.Co + 63) / 64), 256, 0, stream>>>(p);
  };

  // extras chain (BK=128 pipelined 64x64, 64KB LDS; grids < CU count so occupancy
  // cap is irrelevant)
  run64(mkP(f1b, ewb[0], eb[0], nullptr, xe0, nullptr, 1024, 21, 21, 19, 19, 256, 1, 1, 1, 1, 21, 441, 1, 0, 0));
  run64(mkP(xe0, ewb[1], eb[1], nullptr, f2b, nullptr,  256, 21, 21, 10, 10, 512, 9, 3, 2, 0, 12, 144, 1, 0, 0));
  run64(mkP(f2b, ewb[2], eb[2], nullptr, xe2, nullptr,  512, 12, 12, 10, 10, 128, 1, 1, 1, 1, 12, 144, 1, 0, 0));
  run64(mkP(xe2, ewb[3], eb[3], nullptr, f3b, nullptr,  128, 12, 12,  5,  5, 256, 9, 3, 2, 0,  7,  49, 1, 0, 0));
  run64(mkP(f3b, ewb[4], eb[4], nullptr, xe4, nullptr,  256,  7,  7,  5,  5, 128, 1, 1, 1, 1,  5,  25, 0, 0, 0));
  run64(mkP(xe4, ewb[5], eb[5], nullptr, f4b, nullptr,  128,  5,  5,  3,  3, 256, 9, 3, 1, 0,  5,  25, 1, 0, 0));
  run64(mkP(f4b, ewb[6], eb[6], nullptr, xe6, nullptr,  256,  5,  5,  3,  3, 128, 1, 1, 1, 1,  3,   9, 0, 0, 0));
  run64(mkP(xe6, ewb[7], eb[7], nullptr, f5b, nullptr,  128,  3,  3,  1,  1, 256, 9, 3, 1, 0,  3,   9, 1, 0, 0));

  // all 6 heads in ONE launch (long-K head1 first in group enumeration)
  HeadPack h;
  h.L[0] = mkP(f1b, hwb[1], cb[1], bb[1], nullptr, out, 1024, 21, 21, 19, 19, 6 * 85, 9, 3, 1, 0, 0, 0, 0, 6, 5776);
  h.L[1] = mkP(f0b, hwb[0], cb[0], bb[0], nullptr, out,  512, 40, 40, 38, 38, 4 * 85, 9, 3, 1, 0, 0, 0, 0, 4, 0);
  h.L[2] = mkP(f2b, hwb[2], cb[2], bb[2], nullptr, out,  512, 12, 12, 10, 10, 6 * 85, 9, 3, 1, 0, 0, 0, 0, 6, 7942);
  h.L[3] = mkP(f3b, hwb[3], cb[3], bb[3], nullptr, out,  256,  7,  7,  5,  5, 6 * 85, 9, 3, 1, 0, 0, 0, 0, 6, 8542);
  h.L[4] = mkP(f4b, hwb[4], cb[4], bb[4], nullptr, out,  256,  5,  5,  3,  3, 4 * 85, 9, 3, 1, 0, 0, 0, 0, 4, 8692);
  h.L[5] = mkP(f5b, hwb[5], cb[5], bb[5], nullptr, out,  256,  3,  3,  1,  1, 4 * 85, 9, 3, 1, 0, 0, 0, 0, 4, 8728);

  // host precompute: per-layer, per-XCD slot bases for the balanced group mapping
  int gid = 0;
  for (int x = 0; x < 8; ++x) h.sb[x] = 0;
  for (int li = 0; li < 6; ++li) {
    int nbx = (h.L[li].M + 127) / 128;
    h.nbyA[li] = (h.L[li].Co + 127) / 128;
    h.g0[li] = gid & 7;
    for (int x = 0; x < 8; ++x) {
      int f = ((x - gid) % 8 + 8) % 8;                  // first group offset on XCD x
      int cnt = (f < nbx) ? (nbx - f + 7) / 8 : 0;      // groups of this layer on XCD x
      h.sb[(li + 1) * 8 + x] = h.sb[li * 8 + x] + h.nbyA[li] * cnt;
    }
    gid += nbx;
  }
  int maxSlots = 0;
  for (int x = 0; x < 8; ++x) if (h.sb[48 + x] > maxSlots) maxSlots = h.sb[48 + x];
  head_grouped<<<dim3(8 * maxSlots), 512, 0, stream>>>(h);
}